// Round 2
// baseline (656.109 us; speedup 1.0000x reference)
//
#include <hip/hip_runtime.h>
#include <math.h>

#define Nn 100000
#define Cc 256
#define Dd 32
#define Hh 8
#define SEMk 128
#define PAD 32
#define NEG 0.2f

typedef __attribute__((ext_vector_type(8))) short bf16x8;
typedef __attribute__((ext_vector_type(4))) short s16x4;
typedef __attribute__((ext_vector_type(4))) float f32x4;

__device__ __forceinline__ short f2bf(float f) {
    unsigned u = __float_as_uint(f);
    u = (u + 0x7FFF + ((u >> 16) & 1)) >> 16;   // round-to-nearest-even
    return (short)u;
}

// K0a: Wt[j][k] = W[k][j]  (256 x 32 floats)
__global__ __launch_bounds__(256) void k_wtrans(const float* __restrict__ W,
                                                float* __restrict__ Wt) {
    int i = blockIdx.x * 256 + threadIdx.x;
    if (i < Dd * Cc) {
        int j = i >> 5, k = i & 31;
        Wt[i] = W[k * Cc + j];
    }
}

// K0b: fcwb = bf16(fc_w)  (128 x 256)
__global__ __launch_bounds__(256) void k_fcwb(const float* __restrict__ fcw,
                                              short* __restrict__ fcwb) {
    int i = blockIdx.x * 256 + threadIdx.x;
    if (i < SEMk * Cc) fcwb[i] = f2bf(fcw[i]);
}

// K1 (fused): h = x @ W^T, plus per-node attention projections for both layers.
__global__ __launch_bounds__(256) void k_hproj(const float* __restrict__ x,
                                               const float* __restrict__ Wt,
                                               const float* __restrict__ att1,
                                               const float* __restrict__ att2,
                                               float* __restrict__ h,
                                               float* __restrict__ sd1, float* __restrict__ ss1,
                                               float* __restrict__ sd2, float* __restrict__ ss2) {
    __shared__ float4 xs[32 * 65];
    __shared__ float  wt[256 * 36];
    __shared__ float4 hs[32 * 9];
    __shared__ float  a1[8 * 68];
    __shared__ float  a2[8 * 68];

    int t = threadIdx.x;
    int nb = blockIdx.x * 32;

    const float4* xg = (const float4*)x + (size_t)nb * 64;
#pragma unroll
    for (int it = 0; it < 8; ++it) {
        int i = t + it * 256;
        xs[(i >> 6) * 65 + (i & 63)] = xg[i];
    }
    const float4* wg = (const float4*)Wt;
#pragma unroll
    for (int it = 0; it < 8; ++it) {
        int i = t + it * 256;
        *(float4*)&wt[(i >> 3) * 36 + (i & 7) * 4] = wg[i];
    }
#pragma unroll
    for (int it = 0; it < 2; ++it) {
        int i = t + it * 256;
        a1[(i >> 6) * 68 + (i & 63)] = att1[i];
        a2[(i >> 6) * 68 + (i & 63)] = att2[i];
    }
    __syncthreads();

    int nl = t >> 3;
    int dq = t & 7;
    float4 acc = make_float4(0.f, 0.f, 0.f, 0.f);
    const float4* xr = &xs[nl * 65];
#pragma unroll 4
    for (int j4 = 0; j4 < 64; ++j4) {
        float4 xv = xr[j4];
        float4 w0 = *(const float4*)&wt[(j4 * 4 + 0) * 36 + dq * 4];
        float4 w1 = *(const float4*)&wt[(j4 * 4 + 1) * 36 + dq * 4];
        float4 w2 = *(const float4*)&wt[(j4 * 4 + 2) * 36 + dq * 4];
        float4 w3 = *(const float4*)&wt[(j4 * 4 + 3) * 36 + dq * 4];
        acc.x += xv.x * w0.x + xv.y * w1.x + xv.z * w2.x + xv.w * w3.x;
        acc.y += xv.x * w0.y + xv.y * w1.y + xv.z * w2.y + xv.w * w3.y;
        acc.z += xv.x * w0.z + xv.y * w1.z + xv.z * w2.z + xv.w * w3.z;
        acc.w += xv.x * w0.w + xv.y * w1.w + xv.z * w2.w + xv.w * w3.w;
    }
    ((float4*)h)[(size_t)(nb + nl) * 8 + dq] = acc;
    hs[nl * 9 + dq] = acc;
    __syncthreads();

    int nl2 = t >> 3;
    int hh = t & 7;
    float d1 = 0.f, s1 = 0.f, d2 = 0.f, s2 = 0.f;
#pragma unroll
    for (int d4 = 0; d4 < 8; ++d4) {
        float4 hv = hs[nl2 * 9 + d4];
        float4 ad1 = *(const float4*)&a1[hh * 68 + d4 * 4];
        float4 as1 = *(const float4*)&a1[hh * 68 + 32 + d4 * 4];
        float4 ad2 = *(const float4*)&a2[hh * 68 + d4 * 4];
        float4 as2 = *(const float4*)&a2[hh * 68 + 32 + d4 * 4];
        d1 += hv.x * ad1.x + hv.y * ad1.y + hv.z * ad1.z + hv.w * ad1.w;
        s1 += hv.x * as1.x + hv.y * as1.y + hv.z * as1.z + hv.w * as1.w;
        d2 += hv.x * ad2.x + hv.y * ad2.y + hv.z * ad2.z + hv.w * ad2.w;
        s2 += hv.x * as2.x + hv.y * as2.y + hv.z * as2.z + hv.w * as2.w;
    }
    int n = nb + nl2;
    sd1[n * 8 + hh] = d1; ss1[n * 8 + hh] = s1;
    sd2[n * 8 + hh] = d2; ss2[n * 8 + hh] = s2;
}

// K3: scatter edges into padded per-dst slot lists.
__global__ __launch_bounds__(256) void k_scatter(const int* __restrict__ ei, int E,
                                                 int* __restrict__ cnt, int* __restrict__ slots) {
    int e = blockIdx.x * 256 + threadIdx.x;
    if (e >= E) return;
    int s = ei[e];
    int d = ei[E + e];
    int pos = atomicAdd(&cnt[d], 1);
    if (pos < PAD) slots[d * PAD + pos] = s;
}

__device__ __forceinline__ float fast_tanh(float x) {
    return 1.f - 2.f / (1.f + __expf(2.f * x));
}

// K4 (fused GAT + score): block = 512 thr = 8 waves = 8 nodes.
// Gat phase: one wave per node; edges in predicated unroll-8 chunks
//   (all 8 shfls then all 16 gathers issued before any consume -> 4x MLP).
// Score phase: stage 8 nodes' Z as bf16 into a 16-row LDS tile (rows 8..15
//   zeroed; MFMA rows independent so unused rows can't pollute valid ones);
//   wave w computes sem tile w (16 sems) via 8x mfma_16x16x32_bf16,
//   tanh(.+b)*q on D rows 0..7 (quad<2), wave reduce, 1 atomicAdd per block.
__global__ __launch_bounds__(512, 4) void k_gat(const float* __restrict__ h,
                                                const float* __restrict__ sdst,
                                                const float* __restrict__ ssrc,
                                                const int* __restrict__ cnt,
                                                const int* __restrict__ slots,
                                                float* __restrict__ Z,
                                                const short* __restrict__ fcwb,
                                                const float* __restrict__ fcb,
                                                const float* __restrict__ q,
                                                float* __restrict__ Sacc, int bin) {
    __shared__ short zls[16 * 264];     // 8448 B; rows 0..7 = nodes, 8..15 = zero
    __shared__ float partial[8];
    int t = threadIdx.x;
    int lane = t & 63;
    int wid = t >> 6;                   // node-in-block 0..7
    int n = blockIdx.x * 8 + wid;       // grid is exact: Nn/8 blocks

    // zero A rows 8..15 (2112 shorts = 1056 ints)
    for (int i = t; i < 1056; i += 512) ((int*)&zls[8 * 264])[i] = 0;

    int hh = lane >> 3;
    int sub = lane & 7;
    int deg = cnt[n]; if (deg > PAD) deg = PAD;
    float sd = sdst[n * 8 + hh];
    int sval = slots[n * PAD + (lane & 31)];

    float ssum = 0.f;
    float4 acc = make_float4(0.f, 0.f, 0.f, 0.f);
    const float4* h4 = (const float4*)h;
    for (int base = 0; base < deg; base += 8) {
        int s[8];
        float ssv[8];
        float4 hv[8];
#pragma unroll
        for (int i = 0; i < 8; ++i) {
            int si = __shfl(sval, base + i);
            s[i] = (base + i < deg) ? si : n;   // inactive -> safe self address
        }
#pragma unroll
        for (int i = 0; i < 8; ++i) {
            ssv[i] = ssrc[(size_t)s[i] * 8 + hh];
            hv[i]  = h4[(size_t)s[i] * 8 + sub];
        }
#pragma unroll
        for (int i = 0; i < 8; ++i) {
            float ev = sd + ssv[i];
            ev = ev > 0.f ? ev : NEG * ev;
            float w = __expf(ev);
            w = (base + i < deg) ? w : 0.f;     // mask inactive
            acc.x += w * hv[i].x; acc.y += w * hv[i].y;
            acc.z += w * hv[i].z; acc.w += w * hv[i].w;
            ssum += w;
        }
    }
    float inv = 1.f / ssum;
    float4 o;
    o.x = acc.x * inv; o.y = acc.y * inv; o.z = acc.z * inv; o.w = acc.w * inv;
    o.x = o.x > 0.f ? o.x : __expf(o.x) - 1.f;
    o.y = o.y > 0.f ? o.y : __expf(o.y) - 1.f;
    o.z = o.z > 0.f ? o.z : __expf(o.z) - 1.f;
    o.w = o.w > 0.f ? o.w : __expf(o.w) - 1.f;
    ((float4*)Z)[(size_t)n * 64 + lane] = o;

    // stage bf16 row for score MFMA; column index = hh*32+sub*4 = lane*4
    s16x4 b4;
    b4[0] = f2bf(o.x); b4[1] = f2bf(o.y); b4[2] = f2bf(o.z); b4[3] = f2bf(o.w);
    *(s16x4*)&zls[wid * 264 + lane * 4] = b4;
    __syncthreads();

    // score: A = zls rows (8 valid nodes), B = fcwb rows (sems);
    // wave w -> sems [w*16, w*16+16)
    int col = lane & 15;
    int quad = lane >> 4;
    f32x4 sacc;
    sacc[0] = 0.f; sacc[1] = 0.f; sacc[2] = 0.f; sacc[3] = 0.f;
    const short* zrow = &zls[col * 264 + quad * 8];
    const short* brow = fcwb + (size_t)(wid * 16 + col) * Cc + quad * 8;
#pragma unroll
    for (int ks = 0; ks < 8; ++ks) {
        bf16x8 a = *(const bf16x8*)(zrow + ks * 32);
        bf16x8 b = *(const bf16x8*)(brow + ks * 32);
        sacc = __builtin_amdgcn_mfma_f32_16x16x32_bf16(a, b, sacc, 0, 0, 0);
    }
    float local = 0.f;
    if (quad < 2) {                     // D rows 0..7 = the 8 valid nodes
        int sem = wid * 16 + col;
        float bb = fcb[sem], qq = q[sem];
#pragma unroll
        for (int r = 0; r < 4; ++r) local += fast_tanh(sacc[r] + bb) * qq;
    }
#pragma unroll
    for (int off = 32; off > 0; off >>= 1) local += __shfl_down(local, off);
    if (lane == 0) partial[wid] = local;
    __syncthreads();
    if (t == 0) {
        float s = partial[0] + partial[1] + partial[2] + partial[3]
                + partial[4] + partial[5] + partial[6] + partial[7];
        atomicAdd(&Sacc[bin + (blockIdx.x & 15)], s);
    }
}

// K7: out = V0*out + V1*Z2; V from 16+16 score bins (uniform scalar loads).
__global__ __launch_bounds__(256) void k_combine(float* __restrict__ out,
                                                 const float* __restrict__ Z2,
                                                 const float* __restrict__ S) {
    float s1 = 0.f, s2 = 0.f;
#pragma unroll
    for (int i = 0; i < 16; ++i) { s1 += S[i]; s2 += S[16 + i]; }
    s1 *= (1.f / (float)Nn);
    s2 *= (1.f / (float)Nn);
    float mx = fmaxf(s1, s2);
    float e1 = __expf(s1 - mx), e2 = __expf(s2 - mx);
    float inv = 1.f / (e1 + e2);
    float V0 = e1 * inv, V1 = e2 * inv;
    size_t i = (size_t)blockIdx.x * 256 + threadIdx.x;
    if (i < (size_t)Nn * 64) {
        float4 a = ((float4*)out)[i];
        float4 b = ((const float4*)Z2)[i];
        a.x = V0 * a.x + V1 * b.x;
        a.y = V0 * a.y + V1 * b.y;
        a.z = V0 * a.z + V1 * b.z;
        a.w = V0 * a.w + V1 * b.w;
        ((float4*)out)[i] = a;
    }
}

extern "C" void kernel_launch(void* const* d_in, const int* in_sizes, int n_in,
                              void* d_out, int out_size, void* d_ws, size_t ws_size,
                              hipStream_t stream) {
    const float* x    = (const float*)d_in[0];
    const float* W    = (const float*)d_in[1];
    const float* att1 = (const float*)d_in[2];
    const float* att2 = (const float*)d_in[3];
    const float* fcw  = (const float*)d_in[4];
    const float* fcb  = (const float*)d_in[5];
    const float* q    = (const float*)d_in[6];
    const int*   ei1  = (const int*)d_in[7];
    const int*   ei2  = (const int*)d_in[8];
    int E1 = in_sizes[7] / 2;
    int E2 = in_sizes[8] / 2;
    float* out = (float*)d_out;

    char* ws = (char*)d_ws;
    size_t off = 0;
    auto alloc = [&](size_t bytes) -> char* {
        char* p = ws + off;
        off = (off + bytes + 255) & ~(size_t)255;
        return p;
    };
    float* Z2   = (float*)alloc((size_t)Nn * Cc * 4);
    float* h    = (float*)alloc((size_t)Nn * Dd * 4);
    float* sd1  = (float*)alloc((size_t)Nn * Hh * 4);
    float* ss1  = (float*)alloc((size_t)Nn * Hh * 4);
    float* sd2  = (float*)alloc((size_t)Nn * Hh * 4);
    float* ss2  = (float*)alloc((size_t)Nn * Hh * 4);
    int*   cnt  = (int*)alloc((size_t)2 * Nn * 4);
    float* red  = (float*)alloc(256);          // 16 bins S1, 16 bins S2
    float* Wt   = (float*)alloc((size_t)Dd * Cc * 4);
    short* fcwb = (short*)alloc((size_t)SEMk * Cc * 2);
    int*   slt1 = (int*)alloc((size_t)Nn * PAD * 4);
    int*   slt2 = (int*)alloc((size_t)Nn * PAD * 4);
    (void)ws_size; (void)n_in; (void)out_size;

    hipMemsetAsync(cnt, 0, (size_t)2 * Nn * 4, stream);
    hipMemsetAsync(red, 0, 256, stream);

    k_wtrans<<<(Dd * Cc + 255) / 256, 256, 0, stream>>>(W, Wt);
    k_fcwb<<<(SEMk * Cc + 255) / 256, 256, 0, stream>>>(fcw, fcwb);
    k_hproj<<<Nn / 32, 256, 0, stream>>>(x, Wt, att1, att2, h, sd1, ss1, sd2, ss2);
    k_scatter<<<(E1 + 255) / 256, 256, 0, stream>>>(ei1, E1, cnt, slt1);
    k_scatter<<<(E2 + 255) / 256, 256, 0, stream>>>(ei2, E2, cnt + Nn, slt2);
    k_gat<<<Nn / 8, 512, 0, stream>>>(h, sd1, ss1, cnt, slt1, out, fcwb, fcb, q, red, 0);
    k_gat<<<Nn / 8, 512, 0, stream>>>(h, sd2, ss2, cnt + Nn, slt2, Z2, fcwb, fcb, q, red, 16);
    k_combine<<<(Nn * 64) / 256, 256, 0, stream>>>(out, Z2, red);
}

// Round 4
// 574.559 us; speedup vs baseline: 1.1419x; 1.1419x over previous
//
#include <hip/hip_runtime.h>
#include <math.h>

#define Nn 100000
#define Cc 256
#define Dd 32
#define Hh 8
#define SEMk 128
#define PAD 32
#define NEG 0.2f

typedef __attribute__((ext_vector_type(8))) short bf16x8;
typedef __attribute__((ext_vector_type(4))) short s16x4;
typedef __attribute__((ext_vector_type(4))) float f32x4;

__device__ __forceinline__ short f2bf(float f) {
    unsigned u = __float_as_uint(f);
    u = (u + 0x7FFF + ((u >> 16) & 1)) >> 16;   // round-to-nearest-even
    return (short)u;
}

// K0a: Wt[j][k] = W[k][j]  (256 x 32 floats)
__global__ __launch_bounds__(256) void k_wtrans(const float* __restrict__ W,
                                                float* __restrict__ Wt) {
    int i = blockIdx.x * 256 + threadIdx.x;
    if (i < Dd * Cc) {
        int j = i >> 5, k = i & 31;
        Wt[i] = W[k * Cc + j];
    }
}

// K0b: fcwb = bf16(fc_w)  (128 x 256)
__global__ __launch_bounds__(256) void k_fcwb(const float* __restrict__ fcw,
                                              short* __restrict__ fcwb) {
    int i = blockIdx.x * 256 + threadIdx.x;
    if (i < SEMk * Cc) fcwb[i] = f2bf(fcw[i]);
}

// K1 (fused): h = x @ W^T, plus per-node attention projections for both layers.
__global__ __launch_bounds__(256) void k_hproj(const float* __restrict__ x,
                                               const float* __restrict__ Wt,
                                               const float* __restrict__ att1,
                                               const float* __restrict__ att2,
                                               float* __restrict__ h,
                                               float* __restrict__ sd1, float* __restrict__ ss1,
                                               float* __restrict__ sd2, float* __restrict__ ss2) {
    __shared__ float4 xs[32 * 65];
    __shared__ float  wt[256 * 36];
    __shared__ float4 hs[32 * 9];
    __shared__ float  a1[8 * 68];
    __shared__ float  a2[8 * 68];

    int t = threadIdx.x;
    int nb = blockIdx.x * 32;

    const float4* xg = (const float4*)x + (size_t)nb * 64;
#pragma unroll
    for (int it = 0; it < 8; ++it) {
        int i = t + it * 256;
        xs[(i >> 6) * 65 + (i & 63)] = xg[i];
    }
    const float4* wg = (const float4*)Wt;
#pragma unroll
    for (int it = 0; it < 8; ++it) {
        int i = t + it * 256;
        *(float4*)&wt[(i >> 3) * 36 + (i & 7) * 4] = wg[i];
    }
#pragma unroll
    for (int it = 0; it < 2; ++it) {
        int i = t + it * 256;
        a1[(i >> 6) * 68 + (i & 63)] = att1[i];
        a2[(i >> 6) * 68 + (i & 63)] = att2[i];
    }
    __syncthreads();

    int nl = t >> 3;
    int dq = t & 7;
    float4 acc = make_float4(0.f, 0.f, 0.f, 0.f);
    const float4* xr = &xs[nl * 65];
#pragma unroll 4
    for (int j4 = 0; j4 < 64; ++j4) {
        float4 xv = xr[j4];
        float4 w0 = *(const float4*)&wt[(j4 * 4 + 0) * 36 + dq * 4];
        float4 w1 = *(const float4*)&wt[(j4 * 4 + 1) * 36 + dq * 4];
        float4 w2 = *(const float4*)&wt[(j4 * 4 + 2) * 36 + dq * 4];
        float4 w3 = *(const float4*)&wt[(j4 * 4 + 3) * 36 + dq * 4];
        acc.x += xv.x * w0.x + xv.y * w1.x + xv.z * w2.x + xv.w * w3.x;
        acc.y += xv.x * w0.y + xv.y * w1.y + xv.z * w2.y + xv.w * w3.y;
        acc.z += xv.x * w0.z + xv.y * w1.z + xv.z * w2.z + xv.w * w3.z;
        acc.w += xv.x * w0.w + xv.y * w1.w + xv.z * w2.w + xv.w * w3.w;
    }
    ((float4*)h)[(size_t)(nb + nl) * 8 + dq] = acc;
    hs[nl * 9 + dq] = acc;
    __syncthreads();

    int nl2 = t >> 3;
    int hh = t & 7;
    float d1 = 0.f, s1 = 0.f, d2 = 0.f, s2 = 0.f;
#pragma unroll
    for (int d4 = 0; d4 < 8; ++d4) {
        float4 hv = hs[nl2 * 9 + d4];
        float4 ad1 = *(const float4*)&a1[hh * 68 + d4 * 4];
        float4 as1 = *(const float4*)&a1[hh * 68 + 32 + d4 * 4];
        float4 ad2 = *(const float4*)&a2[hh * 68 + d4 * 4];
        float4 as2 = *(const float4*)&a2[hh * 68 + 32 + d4 * 4];
        d1 += hv.x * ad1.x + hv.y * ad1.y + hv.z * ad1.z + hv.w * ad1.w;
        s1 += hv.x * as1.x + hv.y * as1.y + hv.z * as1.z + hv.w * as1.w;
        d2 += hv.x * ad2.x + hv.y * ad2.y + hv.z * ad2.z + hv.w * ad2.w;
        s2 += hv.x * as2.x + hv.y * as2.y + hv.z * as2.z + hv.w * as2.w;
    }
    int n = nb + nl2;
    sd1[n * 8 + hh] = d1; ss1[n * 8 + hh] = s1;
    sd2[n * 8 + hh] = d2; ss2[n * 8 + hh] = s2;
}

// K3: scatter edges into padded per-dst slot lists.
__global__ __launch_bounds__(256) void k_scatter(const int* __restrict__ ei, int E,
                                                 int* __restrict__ cnt, int* __restrict__ slots) {
    int e = blockIdx.x * 256 + threadIdx.x;
    if (e >= E) return;
    int s = ei[e];
    int d = ei[E + e];
    int pos = atomicAdd(&cnt[d], 1);
    if (pos < PAD) slots[d * PAD + pos] = s;
}

// K4: GAT layer, single-pass softmax; one wave per node.
// Chunk-4 software pipeline with NAMED registers (no arrays -> guaranteed SROA):
// issue chunk k+1's 8 gathers before consuming chunk k. Loads complete in
// order so the consume uses a counted vmcnt wait -> ~8 gathers/wave in flight.
__global__ __launch_bounds__(256) void k_gat(const float* __restrict__ h,
                                             const float* __restrict__ sdst,
                                             const float* __restrict__ ssrc,
                                             const int* __restrict__ cnt,
                                             const int* __restrict__ slots,
                                             float* __restrict__ Z) {
    int gid = blockIdx.x * 256 + threadIdx.x;
    int n = gid >> 6;
    int lane = gid & 63;
    if (n >= Nn) return;
    int deg = cnt[n]; if (deg > PAD) deg = PAD;
    int hh = lane >> 3;
    int sub = lane & 7;
    float sd = sdst[n * 8 + hh];
    int sval = slots[n * PAD + (lane & 31)];
    const float4* h4 = (const float4*)h;

    float ssum = 0.f;
    float4 acc = make_float4(0.f, 0.f, 0.f, 0.f);

    // ---- prologue: load chunk at base 0 (deg >= 1 always: self-loop) ----
    int cs0 = __shfl(sval, 0);
    int cs1 = __shfl(sval, 1);
    int cs2 = __shfl(sval, 2);
    int cs3 = __shfl(sval, 3);
    cs1 = (1 < deg) ? cs1 : n;          // inactive -> safe self address
    cs2 = (2 < deg) ? cs2 : n;
    cs3 = (3 < deg) ? cs3 : n;
    float  ca0 = ssrc[(size_t)cs0 * 8 + hh];
    float  ca1 = ssrc[(size_t)cs1 * 8 + hh];
    float  ca2 = ssrc[(size_t)cs2 * 8 + hh];
    float  ca3 = ssrc[(size_t)cs3 * 8 + hh];
    float4 cv0 = h4[(size_t)cs0 * 8 + sub];
    float4 cv1 = h4[(size_t)cs1 * 8 + sub];
    float4 cv2 = h4[(size_t)cs2 * 8 + sub];
    float4 cv3 = h4[(size_t)cs3 * 8 + sub];

    int base = 0;
    for (;;) {
        int nb = base + 4;
        bool more = nb < deg;           // wave-uniform branch
        int ns0, ns1, ns2, ns3;
        float na0, na1, na2, na3;
        float4 nv0, nv1, nv2, nv3;
        if (more) {                     // issue next chunk's 8 gathers NOW
            ns0 = __shfl(sval, nb + 0);
            ns1 = __shfl(sval, nb + 1);
            ns2 = __shfl(sval, nb + 2);
            ns3 = __shfl(sval, nb + 3);
            ns1 = (nb + 1 < deg) ? ns1 : n;
            ns2 = (nb + 2 < deg) ? ns2 : n;
            ns3 = (nb + 3 < deg) ? ns3 : n;
            na0 = ssrc[(size_t)ns0 * 8 + hh];
            na1 = ssrc[(size_t)ns1 * 8 + hh];
            na2 = ssrc[(size_t)ns2 * 8 + hh];
            na3 = ssrc[(size_t)ns3 * 8 + hh];
            nv0 = h4[(size_t)ns0 * 8 + sub];
            nv1 = h4[(size_t)ns1 * 8 + sub];
            nv2 = h4[(size_t)ns2 * 8 + sub];
            nv3 = h4[(size_t)ns3 * 8 + sub];
        }
        // ---- consume current chunk ----
        {
            float ev, w;
            ev = sd + ca0; ev = ev > 0.f ? ev : NEG * ev;
            w = __expf(ev);                                   // base+0 < deg always
            acc.x += w * cv0.x; acc.y += w * cv0.y; acc.z += w * cv0.z; acc.w += w * cv0.w;
            ssum += w;
            ev = sd + ca1; ev = ev > 0.f ? ev : NEG * ev;
            w = __expf(ev); w = (base + 1 < deg) ? w : 0.f;
            acc.x += w * cv1.x; acc.y += w * cv1.y; acc.z += w * cv1.z; acc.w += w * cv1.w;
            ssum += w;
            ev = sd + ca2; ev = ev > 0.f ? ev : NEG * ev;
            w = __expf(ev); w = (base + 2 < deg) ? w : 0.f;
            acc.x += w * cv2.x; acc.y += w * cv2.y; acc.z += w * cv2.z; acc.w += w * cv2.w;
            ssum += w;
            ev = sd + ca3; ev = ev > 0.f ? ev : NEG * ev;
            w = __expf(ev); w = (base + 3 < deg) ? w : 0.f;
            acc.x += w * cv3.x; acc.y += w * cv3.y; acc.z += w * cv3.z; acc.w += w * cv3.w;
            ssum += w;
        }
        if (!more) break;
        base = nb;
        cs0 = ns0; cs1 = ns1; cs2 = ns2; cs3 = ns3;
        ca0 = na0; ca1 = na1; ca2 = na2; ca3 = na3;
        cv0 = nv0; cv1 = nv1; cv2 = nv2; cv3 = nv3;
    }

    float inv = 1.f / ssum;
    float4 o;
    o.x = acc.x * inv; o.y = acc.y * inv; o.z = acc.z * inv; o.w = acc.w * inv;
    o.x = o.x > 0.f ? o.x : __expf(o.x) - 1.f;
    o.y = o.y > 0.f ? o.y : __expf(o.y) - 1.f;
    o.z = o.z > 0.f ? o.z : __expf(o.z) - 1.f;
    o.w = o.w > 0.f ? o.w : __expf(o.w) - 1.f;
    ((float4*)Z)[(size_t)n * 64 + lane] = o;
}

__device__ __forceinline__ float fast_tanh(float x) {
    return 1.f - 2.f / (1.f + __expf(2.f * x));
}

// K5 v3: MFMA score with coalesced LDS staging.
__global__ void k_score(const float* __restrict__ Z,
                        const short* __restrict__ fcwb,
                        const float* __restrict__ fcb,
                        const float* __restrict__ q,
                        float* __restrict__ Sacc) {
    __shared__ short zs[64 * 264];     // 33792 B
    __shared__ float partial[4];
    int t = threadIdx.x;

    const float4* Zg4 = (const float4*)Z + (size_t)blockIdx.x * 4096;
    size_t gmax = (size_t)Nn * 64 - (size_t)blockIdx.x * 4096;
#pragma unroll
    for (int it = 0; it < 16; ++it) {
        int idx = it * 256 + t;
        if ((size_t)idx < gmax) {
            float4 v = Zg4[idx];
            int row = idx >> 6, c4 = idx & 63;
            s16x4 b;
            b[0] = f2bf(v.x); b[1] = f2bf(v.y); b[2] = f2bf(v.z); b[3] = f2bf(v.w);
            *(s16x4*)&zs[row * 264 + c4 * 4] = b;
        }
    }
    __syncthreads();

    int lane = t & 63;
    int wid = t >> 6;
    int nodebase = blockIdx.x * 64 + wid * 16;
    float local = 0.f;
    if (nodebase < Nn) {
        int col = lane & 15;
        int quad = lane >> 4;

        f32x4 acc[8];
#pragma unroll
        for (int tt = 0; tt < 8; ++tt) { acc[tt][0] = 0.f; acc[tt][1] = 0.f; acc[tt][2] = 0.f; acc[tt][3] = 0.f; }

        const short* zrow = &zs[(wid * 16 + col) * 264 + quad * 8];
        const short* brow = fcwb + (size_t)col * Cc + quad * 8;
#pragma unroll
        for (int ks = 0; ks < 8; ++ks) {
            bf16x8 a = *(const bf16x8*)(zrow + ks * 32);
            bf16x8 bf[8];
#pragma unroll
            for (int tt = 0; tt < 8; ++tt)
                bf[tt] = *(const bf16x8*)(brow + tt * 4096 + ks * 32);
#pragma unroll
            for (int tt = 0; tt < 8; ++tt)
                acc[tt] = __builtin_amdgcn_mfma_f32_16x16x32_bf16(a, bf[tt], acc[tt], 0, 0, 0);
        }

#pragma unroll
        for (int tt = 0; tt < 8; ++tt) {
            int n = tt * 16 + col;
            float b = fcb[n], qq = q[n];
#pragma unroll
            for (int r = 0; r < 4; ++r) local += fast_tanh(acc[tt][r] + b) * qq;
        }
    }
#pragma unroll
    for (int off = 32; off > 0; off >>= 1) local += __shfl_down(local, off);
    if (lane == 0) partial[wid] = local;
    __syncthreads();
    if (t == 0) {
        float s = partial[0] + partial[1] + partial[2] + partial[3];
        atomicAdd(&Sacc[blockIdx.x & 15], s);
    }
}

// K7: out = V0*out + V1*Z2; V from 16+16 score bins (uniform scalar loads).
__global__ __launch_bounds__(256) void k_combine(float* __restrict__ out,
                                                 const float* __restrict__ Z2,
                                                 const float* __restrict__ S) {
    float s1 = 0.f, s2 = 0.f;
#pragma unroll
    for (int i = 0; i < 16; ++i) { s1 += S[i]; s2 += S[16 + i]; }
    s1 *= (1.f / (float)Nn);
    s2 *= (1.f / (float)Nn);
    float mx = fmaxf(s1, s2);
    float e1 = __expf(s1 - mx), e2 = __expf(s2 - mx);
    float inv = 1.f / (e1 + e2);
    float V0 = e1 * inv, V1 = e2 * inv;
    size_t i = (size_t)blockIdx.x * 256 + threadIdx.x;
    if (i < (size_t)Nn * 64) {
        float4 a = ((float4*)out)[i];
        float4 b = ((const float4*)Z2)[i];
        a.x = V0 * a.x + V1 * b.x;
        a.y = V0 * a.y + V1 * b.y;
        a.z = V0 * a.z + V1 * b.z;
        a.w = V0 * a.w + V1 * b.w;
        ((float4*)out)[i] = a;
    }
}

extern "C" void kernel_launch(void* const* d_in, const int* in_sizes, int n_in,
                              void* d_out, int out_size, void* d_ws, size_t ws_size,
                              hipStream_t stream) {
    const float* x    = (const float*)d_in[0];
    const float* W    = (const float*)d_in[1];
    const float* att1 = (const float*)d_in[2];
    const float* att2 = (const float*)d_in[3];
    const float* fcw  = (const float*)d_in[4];
    const float* fcb  = (const float*)d_in[5];
    const float* q    = (const float*)d_in[6];
    const int*   ei1  = (const int*)d_in[7];
    const int*   ei2  = (const int*)d_in[8];
    int E1 = in_sizes[7] / 2;
    int E2 = in_sizes[8] / 2;
    float* out = (float*)d_out;

    char* ws = (char*)d_ws;
    size_t off = 0;
    auto alloc = [&](size_t bytes) -> char* {
        char* p = ws + off;
        off = (off + bytes + 255) & ~(size_t)255;
        return p;
    };
    float* Z2   = (float*)alloc((size_t)Nn * Cc * 4);
    float* h    = (float*)alloc((size_t)Nn * Dd * 4);
    float* sd1  = (float*)alloc((size_t)Nn * Hh * 4);
    float* ss1  = (float*)alloc((size_t)Nn * Hh * 4);
    float* sd2  = (float*)alloc((size_t)Nn * Hh * 4);
    float* ss2  = (float*)alloc((size_t)Nn * Hh * 4);
    int*   cnt  = (int*)alloc((size_t)2 * Nn * 4);
    float* red  = (float*)alloc(256);          // 16 bins S1, 16 bins S2
    float* Wt   = (float*)alloc((size_t)Dd * Cc * 4);
    short* fcwb = (short*)alloc((size_t)SEMk * Cc * 2);
    int*   slt1 = (int*)alloc((size_t)Nn * PAD * 4);
    int*   slt2 = (int*)alloc((size_t)Nn * PAD * 4);
    (void)ws_size; (void)n_in; (void)out_size;

    hipMemsetAsync(cnt, 0, (size_t)2 * Nn * 4, stream);
    hipMemsetAsync(red, 0, 256, stream);

    k_wtrans<<<(Dd * Cc + 255) / 256, 256, 0, stream>>>(W, Wt);
    k_fcwb<<<(SEMk * Cc + 255) / 256, 256, 0, stream>>>(fcw, fcwb);
    k_hproj<<<Nn / 32, 256, 0, stream>>>(x, Wt, att1, att2, h, sd1, ss1, sd2, ss2);
    k_scatter<<<(E1 + 255) / 256, 256, 0, stream>>>(ei1, E1, cnt, slt1);
    k_scatter<<<(E2 + 255) / 256, 256, 0, stream>>>(ei2, E2, cnt + Nn, slt2);
    k_gat<<<(Nn * 64) / 256, 256, 0, stream>>>(h, sd1, ss1, cnt, slt1, out);
    k_gat<<<(Nn * 64) / 256, 256, 0, stream>>>(h, sd2, ss2, cnt + Nn, slt2, Z2);
    int nblk = (Nn + 63) / 64;                 // 1563
    k_score<<<nblk, 256, 0, stream>>>(out, fcwb, fcb, q, red);
    k_score<<<nblk, 256, 0, stream>>>(Z2, fcwb, fcb, q, red + 16);
    k_combine<<<(Nn * 64) / 256, 256, 0, stream>>>(out, Z2, red);
}

// Round 5
// 565.174 us; speedup vs baseline: 1.1609x; 1.0166x over previous
//
#include <hip/hip_runtime.h>
#include <math.h>

#define Nn 100000
#define Cc 256
#define Dd 32
#define Hh 8
#define SEMk 128
#define PAD 32
#define NEG 0.2f

typedef __attribute__((ext_vector_type(8))) short bf16x8;
typedef __attribute__((ext_vector_type(4))) short s16x4;
typedef __attribute__((ext_vector_type(4))) float f32x4;

__device__ __forceinline__ short f2bf(float f) {
    unsigned u = __float_as_uint(f);
    u = (u + 0x7FFF + ((u >> 16) & 1)) >> 16;   // round-to-nearest-even
    return (short)u;
}

// K0a: Wt[j][k] = W[k][j]  (256 x 32 floats)
__global__ __launch_bounds__(256) void k_wtrans(const float* __restrict__ W,
                                                float* __restrict__ Wt) {
    int i = blockIdx.x * 256 + threadIdx.x;
    if (i < Dd * Cc) {
        int j = i >> 5, k = i & 31;
        Wt[i] = W[k * Cc + j];
    }
}

// K0b: fcwb = bf16(fc_w)  (128 x 256)
__global__ __launch_bounds__(256) void k_fcwb(const float* __restrict__ fcw,
                                              short* __restrict__ fcwb) {
    int i = blockIdx.x * 256 + threadIdx.x;
    if (i < SEMk * Cc) fcwb[i] = f2bf(fcw[i]);
}

// K1 (fused): h = x @ W^T, plus per-node attention projections for both layers.
__global__ __launch_bounds__(256) void k_hproj(const float* __restrict__ x,
                                               const float* __restrict__ Wt,
                                               const float* __restrict__ att1,
                                               const float* __restrict__ att2,
                                               float* __restrict__ h,
                                               float* __restrict__ sd1, float* __restrict__ ss1,
                                               float* __restrict__ sd2, float* __restrict__ ss2) {
    __shared__ float4 xs[32 * 65];
    __shared__ float  wt[256 * 36];
    __shared__ float4 hs[32 * 9];
    __shared__ float  a1[8 * 68];
    __shared__ float  a2[8 * 68];

    int t = threadIdx.x;
    int nb = blockIdx.x * 32;

    const float4* xg = (const float4*)x + (size_t)nb * 64;
#pragma unroll
    for (int it = 0; it < 8; ++it) {
        int i = t + it * 256;
        xs[(i >> 6) * 65 + (i & 63)] = xg[i];
    }
    const float4* wg = (const float4*)Wt;
#pragma unroll
    for (int it = 0; it < 8; ++it) {
        int i = t + it * 256;
        *(float4*)&wt[(i >> 3) * 36 + (i & 7) * 4] = wg[i];
    }
#pragma unroll
    for (int it = 0; it < 2; ++it) {
        int i = t + it * 256;
        a1[(i >> 6) * 68 + (i & 63)] = att1[i];
        a2[(i >> 6) * 68 + (i & 63)] = att2[i];
    }
    __syncthreads();

    int nl = t >> 3;
    int dq = t & 7;
    float4 acc = make_float4(0.f, 0.f, 0.f, 0.f);
    const float4* xr = &xs[nl * 65];
#pragma unroll 4
    for (int j4 = 0; j4 < 64; ++j4) {
        float4 xv = xr[j4];
        float4 w0 = *(const float4*)&wt[(j4 * 4 + 0) * 36 + dq * 4];
        float4 w1 = *(const float4*)&wt[(j4 * 4 + 1) * 36 + dq * 4];
        float4 w2 = *(const float4*)&wt[(j4 * 4 + 2) * 36 + dq * 4];
        float4 w3 = *(const float4*)&wt[(j4 * 4 + 3) * 36 + dq * 4];
        acc.x += xv.x * w0.x + xv.y * w1.x + xv.z * w2.x + xv.w * w3.x;
        acc.y += xv.x * w0.y + xv.y * w1.y + xv.z * w2.y + xv.w * w3.y;
        acc.z += xv.x * w0.z + xv.y * w1.z + xv.z * w2.z + xv.w * w3.z;
        acc.w += xv.x * w0.w + xv.y * w1.w + xv.z * w2.w + xv.w * w3.w;
    }
    ((float4*)h)[(size_t)(nb + nl) * 8 + dq] = acc;
    hs[nl * 9 + dq] = acc;
    __syncthreads();

    int nl2 = t >> 3;
    int hh = t & 7;
    float d1 = 0.f, s1 = 0.f, d2 = 0.f, s2 = 0.f;
#pragma unroll
    for (int d4 = 0; d4 < 8; ++d4) {
        float4 hv = hs[nl2 * 9 + d4];
        float4 ad1 = *(const float4*)&a1[hh * 68 + d4 * 4];
        float4 as1 = *(const float4*)&a1[hh * 68 + 32 + d4 * 4];
        float4 ad2 = *(const float4*)&a2[hh * 68 + d4 * 4];
        float4 as2 = *(const float4*)&a2[hh * 68 + 32 + d4 * 4];
        d1 += hv.x * ad1.x + hv.y * ad1.y + hv.z * ad1.z + hv.w * ad1.w;
        s1 += hv.x * as1.x + hv.y * as1.y + hv.z * as1.z + hv.w * as1.w;
        d2 += hv.x * ad2.x + hv.y * ad2.y + hv.z * ad2.z + hv.w * ad2.w;
        s2 += hv.x * as2.x + hv.y * as2.y + hv.z * as2.z + hv.w * as2.w;
    }
    int n = nb + nl2;
    sd1[n * 8 + hh] = d1; ss1[n * 8 + hh] = s1;
    sd2[n * 8 + hh] = d2; ss2[n * 8 + hh] = s2;
}

// K3: scatter edges into padded per-dst slot lists.
__global__ __launch_bounds__(256) void k_scatter(const int* __restrict__ ei, int E,
                                                 int* __restrict__ cnt, int* __restrict__ slots) {
    int e = blockIdx.x * 256 + threadIdx.x;
    if (e >= E) return;
    int s = ei[e];
    int d = ei[E + e];
    int pos = atomicAdd(&cnt[d], 1);
    if (pos < PAD) slots[d * PAD + pos] = s;
}

// K4: GAT layer, single-pass softmax; one wave per node.
// Chunk-4 software pipeline with NAMED registers (no arrays -> guaranteed SROA):
// issue chunk k+1's 8 gathers before consuming chunk k.
__global__ __launch_bounds__(256) void k_gat(const float* __restrict__ h,
                                             const float* __restrict__ sdst,
                                             const float* __restrict__ ssrc,
                                             const int* __restrict__ cnt,
                                             const int* __restrict__ slots,
                                             float* __restrict__ Z) {
    int gid = blockIdx.x * 256 + threadIdx.x;
    int n = gid >> 6;
    int lane = gid & 63;
    if (n >= Nn) return;
    int deg = cnt[n]; if (deg > PAD) deg = PAD;
    int hh = lane >> 3;
    int sub = lane & 7;
    float sd = sdst[n * 8 + hh];
    int sval = slots[n * PAD + (lane & 31)];
    const float4* h4 = (const float4*)h;

    float ssum = 0.f;
    float4 acc = make_float4(0.f, 0.f, 0.f, 0.f);

    // ---- prologue: load chunk at base 0 (deg >= 1 always: self-loop) ----
    int cs0 = __shfl(sval, 0);
    int cs1 = __shfl(sval, 1);
    int cs2 = __shfl(sval, 2);
    int cs3 = __shfl(sval, 3);
    cs1 = (1 < deg) ? cs1 : n;          // inactive -> safe self address
    cs2 = (2 < deg) ? cs2 : n;
    cs3 = (3 < deg) ? cs3 : n;
    float  ca0 = ssrc[(size_t)cs0 * 8 + hh];
    float  ca1 = ssrc[(size_t)cs1 * 8 + hh];
    float  ca2 = ssrc[(size_t)cs2 * 8 + hh];
    float  ca3 = ssrc[(size_t)cs3 * 8 + hh];
    float4 cv0 = h4[(size_t)cs0 * 8 + sub];
    float4 cv1 = h4[(size_t)cs1 * 8 + sub];
    float4 cv2 = h4[(size_t)cs2 * 8 + sub];
    float4 cv3 = h4[(size_t)cs3 * 8 + sub];

    int base = 0;
    for (;;) {
        int nb = base + 4;
        bool more = nb < deg;           // wave-uniform branch
        int ns0, ns1, ns2, ns3;
        float na0, na1, na2, na3;
        float4 nv0, nv1, nv2, nv3;
        if (more) {                     // issue next chunk's 8 gathers NOW
            ns0 = __shfl(sval, nb + 0);
            ns1 = __shfl(sval, nb + 1);
            ns2 = __shfl(sval, nb + 2);
            ns3 = __shfl(sval, nb + 3);
            ns1 = (nb + 1 < deg) ? ns1 : n;
            ns2 = (nb + 2 < deg) ? ns2 : n;
            ns3 = (nb + 3 < deg) ? ns3 : n;
            na0 = ssrc[(size_t)ns0 * 8 + hh];
            na1 = ssrc[(size_t)ns1 * 8 + hh];
            na2 = ssrc[(size_t)ns2 * 8 + hh];
            na3 = ssrc[(size_t)ns3 * 8 + hh];
            nv0 = h4[(size_t)ns0 * 8 + sub];
            nv1 = h4[(size_t)ns1 * 8 + sub];
            nv2 = h4[(size_t)ns2 * 8 + sub];
            nv3 = h4[(size_t)ns3 * 8 + sub];
        }
        // ---- consume current chunk ----
        {
            float ev, w;
            ev = sd + ca0; ev = ev > 0.f ? ev : NEG * ev;
            w = __expf(ev);                                   // base+0 < deg always
            acc.x += w * cv0.x; acc.y += w * cv0.y; acc.z += w * cv0.z; acc.w += w * cv0.w;
            ssum += w;
            ev = sd + ca1; ev = ev > 0.f ? ev : NEG * ev;
            w = __expf(ev); w = (base + 1 < deg) ? w : 0.f;
            acc.x += w * cv1.x; acc.y += w * cv1.y; acc.z += w * cv1.z; acc.w += w * cv1.w;
            ssum += w;
            ev = sd + ca2; ev = ev > 0.f ? ev : NEG * ev;
            w = __expf(ev); w = (base + 2 < deg) ? w : 0.f;
            acc.x += w * cv2.x; acc.y += w * cv2.y; acc.z += w * cv2.z; acc.w += w * cv2.w;
            ssum += w;
            ev = sd + ca3; ev = ev > 0.f ? ev : NEG * ev;
            w = __expf(ev); w = (base + 3 < deg) ? w : 0.f;
            acc.x += w * cv3.x; acc.y += w * cv3.y; acc.z += w * cv3.z; acc.w += w * cv3.w;
            ssum += w;
        }
        if (!more) break;
        base = nb;
        cs0 = ns0; cs1 = ns1; cs2 = ns2; cs3 = ns3;
        ca0 = na0; ca1 = na1; ca2 = na2; ca3 = na3;
        cv0 = nv0; cv1 = nv1; cv2 = nv2; cv3 = nv3;
    }

    float inv = 1.f / ssum;
    float4 o;
    o.x = acc.x * inv; o.y = acc.y * inv; o.z = acc.z * inv; o.w = acc.w * inv;
    o.x = o.x > 0.f ? o.x : __expf(o.x) - 1.f;
    o.y = o.y > 0.f ? o.y : __expf(o.y) - 1.f;
    o.z = o.z > 0.f ? o.z : __expf(o.z) - 1.f;
    o.w = o.w > 0.f ? o.w : __expf(o.w) - 1.f;
    ((float4*)Z)[(size_t)n * 64 + lane] = o;
}

__device__ __forceinline__ float fast_tanh(float x) {
    return 1.f - 2.f / (1.f + __expf(2.f * x));
}

// K5 v4: wave-independent MFMA score. No LDS, no barrier.
// Wave w of each block owns 16 nodes. A-fragment for mfma_16x16x32_bf16 is
// loaded DIRECTLY from global Z: lane(col,quad) reads
// Z[(base+col)*256 + ks*32 + quad*8 .. +8] (two float4, 128B-contiguous per
// row across quads) and converts to bf16 in-register. Same fragment mapping
// as the harness-validated LDS version. B from global fcwb (L1/L2-resident).
// Reduce: wave shfl -> one atomicAdd per wave into bins spread 64B apart.
__global__ __launch_bounds__(256) void k_score(const float* __restrict__ Z,
                        const short* __restrict__ fcwb,
                        const float* __restrict__ fcb,
                        const float* __restrict__ q,
                        float* __restrict__ Sacc) {
    int t = threadIdx.x;
    int lane = t & 63;
    int wid = t >> 6;
    int nodebase = blockIdx.x * 64 + wid * 16;
    if (nodebase >= Nn) return;       // Nn % 16 == 0, wave-granular guard ok
    int col = lane & 15;
    int quad = lane >> 4;

    // load + convert all 8 A-fragments (16 float4 loads issue back-to-back)
    const float* zp = Z + (size_t)(nodebase + col) * Cc + quad * 8;
    bf16x8 af[8];
#pragma unroll
    for (int ks = 0; ks < 8; ++ks) {
        float4 f0 = *(const float4*)(zp + ks * 32);
        float4 f1 = *(const float4*)(zp + ks * 32 + 4);
        bf16x8 a;
        a[0] = f2bf(f0.x); a[1] = f2bf(f0.y); a[2] = f2bf(f0.z); a[3] = f2bf(f0.w);
        a[4] = f2bf(f1.x); a[5] = f2bf(f1.y); a[6] = f2bf(f1.z); a[7] = f2bf(f1.w);
        af[ks] = a;
    }

    f32x4 acc[8];
#pragma unroll
    for (int tt = 0; tt < 8; ++tt) { acc[tt][0] = 0.f; acc[tt][1] = 0.f; acc[tt][2] = 0.f; acc[tt][3] = 0.f; }

    const short* brow = fcwb + (size_t)col * Cc + quad * 8;
#pragma unroll
    for (int ks = 0; ks < 8; ++ks) {
#pragma unroll
        for (int tt = 0; tt < 8; ++tt) {
            bf16x8 b = *(const bf16x8*)(brow + tt * 4096 + ks * 32);
            acc[tt] = __builtin_amdgcn_mfma_f32_16x16x32_bf16(af[ks], b, acc[tt], 0, 0, 0);
        }
    }

    float local = 0.f;
#pragma unroll
    for (int tt = 0; tt < 8; ++tt) {
        int sem = tt * 16 + col;
        float b = fcb[sem], qq = q[sem];
#pragma unroll
        for (int r = 0; r < 4; ++r) local += fast_tanh(acc[tt][r] + b) * qq;
    }
#pragma unroll
    for (int off = 32; off > 0; off >>= 1) local += __shfl_down(local, off);
    if (lane == 0) atomicAdd(&Sacc[(blockIdx.x & 15) * 16], local);
}

// K7: out = V0*out + V1*Z2; V from 16+16 score bins (stride-16 layout).
__global__ __launch_bounds__(256) void k_combine(float* __restrict__ out,
                                                 const float* __restrict__ Z2,
                                                 const float* __restrict__ S) {
    float s1 = 0.f, s2 = 0.f;
#pragma unroll
    for (int i = 0; i < 16; ++i) { s1 += S[i * 16]; s2 += S[256 + i * 16]; }
    s1 *= (1.f / (float)Nn);
    s2 *= (1.f / (float)Nn);
    float mx = fmaxf(s1, s2);
    float e1 = __expf(s1 - mx), e2 = __expf(s2 - mx);
    float inv = 1.f / (e1 + e2);
    float V0 = e1 * inv, V1 = e2 * inv;
    size_t i = (size_t)blockIdx.x * 256 + threadIdx.x;
    if (i < (size_t)Nn * 64) {
        float4 a = ((float4*)out)[i];
        float4 b = ((const float4*)Z2)[i];
        a.x = V0 * a.x + V1 * b.x;
        a.y = V0 * a.y + V1 * b.y;
        a.z = V0 * a.z + V1 * b.z;
        a.w = V0 * a.w + V1 * b.w;
        ((float4*)out)[i] = a;
    }
}

extern "C" void kernel_launch(void* const* d_in, const int* in_sizes, int n_in,
                              void* d_out, int out_size, void* d_ws, size_t ws_size,
                              hipStream_t stream) {
    const float* x    = (const float*)d_in[0];
    const float* W    = (const float*)d_in[1];
    const float* att1 = (const float*)d_in[2];
    const float* att2 = (const float*)d_in[3];
    const float* fcw  = (const float*)d_in[4];
    const float* fcb  = (const float*)d_in[5];
    const float* q    = (const float*)d_in[6];
    const int*   ei1  = (const int*)d_in[7];
    const int*   ei2  = (const int*)d_in[8];
    int E1 = in_sizes[7] / 2;
    int E2 = in_sizes[8] / 2;
    float* out = (float*)d_out;

    char* ws = (char*)d_ws;
    size_t off = 0;
    auto alloc = [&](size_t bytes) -> char* {
        char* p = ws + off;
        off = (off + bytes + 255) & ~(size_t)255;
        return p;
    };
    float* Z2   = (float*)alloc((size_t)Nn * Cc * 4);
    float* h    = (float*)alloc((size_t)Nn * Dd * 4);
    float* sd1  = (float*)alloc((size_t)Nn * Hh * 4);
    float* ss1  = (float*)alloc((size_t)Nn * Hh * 4);
    float* sd2  = (float*)alloc((size_t)Nn * Hh * 4);
    float* ss2  = (float*)alloc((size_t)Nn * Hh * 4);
    int*   cnt  = (int*)alloc((size_t)2 * Nn * 4);
    float* red  = (float*)alloc(2048);         // 2 sets x 16 bins, stride 16 floats
    float* Wt   = (float*)alloc((size_t)Dd * Cc * 4);
    short* fcwb = (short*)alloc((size_t)SEMk * Cc * 2);
    int*   slt1 = (int*)alloc((size_t)Nn * PAD * 4);
    int*   slt2 = (int*)alloc((size_t)Nn * PAD * 4);
    (void)ws_size; (void)n_in; (void)out_size;

    hipMemsetAsync(cnt, 0, (size_t)2 * Nn * 4, stream);
    hipMemsetAsync(red, 0, 2048, stream);

    k_wtrans<<<(Dd * Cc + 255) / 256, 256, 0, stream>>>(W, Wt);
    k_fcwb<<<(SEMk * Cc + 255) / 256, 256, 0, stream>>>(fcw, fcwb);
    k_hproj<<<Nn / 32, 256, 0, stream>>>(x, Wt, att1, att2, h, sd1, ss1, sd2, ss2);
    k_scatter<<<(E1 + 255) / 256, 256, 0, stream>>>(ei1, E1, cnt, slt1);
    k_scatter<<<(E2 + 255) / 256, 256, 0, stream>>>(ei2, E2, cnt + Nn, slt2);
    k_gat<<<(Nn * 64) / 256, 256, 0, stream>>>(h, sd1, ss1, cnt, slt1, out);
    k_gat<<<(Nn * 64) / 256, 256, 0, stream>>>(h, sd2, ss2, cnt + Nn, slt2, Z2);
    int nblk = (Nn + 63) / 64;                 // 1563
    k_score<<<nblk, 256, 0, stream>>>(out, fcwb, fcb, q, red);
    k_score<<<nblk, 256, 0, stream>>>(Z2, fcwb, fcb, q, red + 256);
    k_combine<<<(Nn * 64) / 256, 256, 0, stream>>>(out, Z2, red);
}

// Round 6
// 543.445 us; speedup vs baseline: 1.2073x; 1.0400x over previous
//
#include <hip/hip_runtime.h>
#include <math.h>

#define Nn 100000
#define Cc 256
#define Dd 32
#define Hh 8
#define SEMk 128
#define PAD 32
#define NEG 0.2f
#define NB1 25000          // k_gat blocks per layer (4 nodes/block)
#define NBS 1563           // k_score blocks per layer (64 nodes/block)

#if __has_builtin(__builtin_amdgcn_exp2f)
#define EXP2(x) __builtin_amdgcn_exp2f(x)
#else
#define EXP2(x) exp2f(x)
#endif
#define LOG2E 1.44269504088896f

typedef __attribute__((ext_vector_type(8))) short bf16x8;
typedef __attribute__((ext_vector_type(4))) short s16x4;
typedef __attribute__((ext_vector_type(4))) float f32x4;

__device__ __forceinline__ short f2bf(float f) {
    unsigned u = __float_as_uint(f);
    u = (u + 0x7FFF + ((u >> 16) & 1)) >> 16;   // round-to-nearest-even
    return (short)u;
}

// K0: Wt[j][k] = W[k][j] and fcwb = bf16(fc_w), one launch.
__global__ __launch_bounds__(256) void k_prep(const float* __restrict__ W,
                                              float* __restrict__ Wt,
                                              const float* __restrict__ fcw,
                                              short* __restrict__ fcwb) {
    int i = blockIdx.x * 256 + threadIdx.x;
    if (i < Dd * Cc) {
        int j = i >> 5, k = i & 31;
        Wt[i] = W[k * Cc + j];
    }
    if (i < SEMk * Cc) fcwb[i] = f2bf(fcw[i]);
}

// K1 (fused): h = x @ W^T, plus per-node attention projections for both layers.
// Scores are pre-scaled by log2e so k_gat can use bare v_exp_f32 (2^x):
// exp(leaky(d+s)) == 2^(leaky(L*d + L*s)) since leaky commutes with L>0.
__global__ __launch_bounds__(256) void k_hproj(const float* __restrict__ x,
                                               const float* __restrict__ Wt,
                                               const float* __restrict__ att1,
                                               const float* __restrict__ att2,
                                               float* __restrict__ h,
                                               float* __restrict__ sd1, float* __restrict__ ss1,
                                               float* __restrict__ sd2, float* __restrict__ ss2) {
    __shared__ float4 xs[32 * 65];
    __shared__ float  wt[256 * 36];
    __shared__ float4 hs[32 * 9];
    __shared__ float  a1[8 * 68];
    __shared__ float  a2[8 * 68];

    int t = threadIdx.x;
    int nb = blockIdx.x * 32;

    const float4* xg = (const float4*)x + (size_t)nb * 64;
#pragma unroll
    for (int it = 0; it < 8; ++it) {
        int i = t + it * 256;
        xs[(i >> 6) * 65 + (i & 63)] = xg[i];
    }
    const float4* wg = (const float4*)Wt;
#pragma unroll
    for (int it = 0; it < 8; ++it) {
        int i = t + it * 256;
        *(float4*)&wt[(i >> 3) * 36 + (i & 7) * 4] = wg[i];
    }
#pragma unroll
    for (int it = 0; it < 2; ++it) {
        int i = t + it * 256;
        a1[(i >> 6) * 68 + (i & 63)] = att1[i];
        a2[(i >> 6) * 68 + (i & 63)] = att2[i];
    }
    __syncthreads();

    int nl = t >> 3;
    int dq = t & 7;
    float4 acc = make_float4(0.f, 0.f, 0.f, 0.f);
    const float4* xr = &xs[nl * 65];
#pragma unroll 4
    for (int j4 = 0; j4 < 64; ++j4) {
        float4 xv = xr[j4];
        float4 w0 = *(const float4*)&wt[(j4 * 4 + 0) * 36 + dq * 4];
        float4 w1 = *(const float4*)&wt[(j4 * 4 + 1) * 36 + dq * 4];
        float4 w2 = *(const float4*)&wt[(j4 * 4 + 2) * 36 + dq * 4];
        float4 w3 = *(const float4*)&wt[(j4 * 4 + 3) * 36 + dq * 4];
        acc.x += xv.x * w0.x + xv.y * w1.x + xv.z * w2.x + xv.w * w3.x;
        acc.y += xv.x * w0.y + xv.y * w1.y + xv.z * w2.y + xv.w * w3.y;
        acc.z += xv.x * w0.z + xv.y * w1.z + xv.z * w2.z + xv.w * w3.z;
        acc.w += xv.x * w0.w + xv.y * w1.w + xv.z * w2.w + xv.w * w3.w;
    }
    ((float4*)h)[(size_t)(nb + nl) * 8 + dq] = acc;
    hs[nl * 9 + dq] = acc;
    __syncthreads();

    int nl2 = t >> 3;
    int hh = t & 7;
    float d1 = 0.f, s1 = 0.f, d2 = 0.f, s2 = 0.f;
#pragma unroll
    for (int d4 = 0; d4 < 8; ++d4) {
        float4 hv = hs[nl2 * 9 + d4];
        float4 ad1 = *(const float4*)&a1[hh * 68 + d4 * 4];
        float4 as1 = *(const float4*)&a1[hh * 68 + 32 + d4 * 4];
        float4 ad2 = *(const float4*)&a2[hh * 68 + d4 * 4];
        float4 as2 = *(const float4*)&a2[hh * 68 + 32 + d4 * 4];
        d1 += hv.x * ad1.x + hv.y * ad1.y + hv.z * ad1.z + hv.w * ad1.w;
        s1 += hv.x * as1.x + hv.y * as1.y + hv.z * as1.z + hv.w * as1.w;
        d2 += hv.x * ad2.x + hv.y * ad2.y + hv.z * ad2.z + hv.w * ad2.w;
        s2 += hv.x * as2.x + hv.y * as2.y + hv.z * as2.z + hv.w * as2.w;
    }
    int n = nb + nl2;
    sd1[n * 8 + hh] = d1 * LOG2E; ss1[n * 8 + hh] = s1 * LOG2E;
    sd2[n * 8 + hh] = d2 * LOG2E; ss2[n * 8 + hh] = s2 * LOG2E;
}

// K3: scatter edges of BOTH layers into padded per-dst slot lists, one launch.
__global__ __launch_bounds__(256) void k_scatter(const int* __restrict__ ei1, int E1,
                                                 const int* __restrict__ ei2, int E2,
                                                 int* __restrict__ cnt,
                                                 int* __restrict__ slt1,
                                                 int* __restrict__ slt2) {
    int id = blockIdx.x * 256 + threadIdx.x;
    const int* ei; int e, EE; int* c; int* sl;
    if (id < E1) { ei = ei1; e = id; EE = E1; c = cnt; sl = slt1; }
    else {
        e = id - E1;
        if (e >= E2) return;
        ei = ei2; EE = E2; c = cnt + Nn; sl = slt2;
    }
    int s = ei[e];
    int d = ei[EE + e];
    int pos = atomicAdd(&c[d], 1);
    if (pos < PAD) sl[d * PAD + pos] = s;
}

// ---- k_gat helper macros: load one chunk of 4 edges / consume it ----
#define LOADC(S0,S1,S2,S3,A0,A1,A2,A3,V0,V1,V2,V3,BB) do {                         \
    S0 = __shfl(sval, (BB) + 0); S1 = __shfl(sval, (BB) + 1);                      \
    S2 = __shfl(sval, (BB) + 2); S3 = __shfl(sval, (BB) + 3);                      \
    S1 = ((BB) + 1 < deg) ? S1 : n;                                                \
    S2 = ((BB) + 2 < deg) ? S2 : n;                                                \
    S3 = ((BB) + 3 < deg) ? S3 : n;                                                \
    A0 = ssrc[(unsigned)S0 * 8u + hh]; A1 = ssrc[(unsigned)S1 * 8u + hh];          \
    A2 = ssrc[(unsigned)S2 * 8u + hh]; A3 = ssrc[(unsigned)S3 * 8u + hh];          \
    V0 = h4[(unsigned)S0 * 8u + sub];  V1 = h4[(unsigned)S1 * 8u + sub];           \
    V2 = h4[(unsigned)S2 * 8u + sub];  V3 = h4[(unsigned)S3 * 8u + sub];           \
} while (0)

#define CONS(A0,A1,A2,A3,V0,V1,V2,V3,BB) do {                                      \
    float ev_, w_;                                                                 \
    ev_ = sd + A0; ev_ = ev_ > 0.f ? ev_ : NEG * ev_; w_ = EXP2(ev_);              \
    acc.x += w_ * V0.x; acc.y += w_ * V0.y; acc.z += w_ * V0.z; acc.w += w_ * V0.w; ssum += w_; \
    ev_ = sd + A1; ev_ = ev_ > 0.f ? ev_ : NEG * ev_; w_ = EXP2(ev_);              \
    w_ = ((BB) + 1 < deg) ? w_ : 0.f;                                              \
    acc.x += w_ * V1.x; acc.y += w_ * V1.y; acc.z += w_ * V1.z; acc.w += w_ * V1.w; ssum += w_; \
    ev_ = sd + A2; ev_ = ev_ > 0.f ? ev_ : NEG * ev_; w_ = EXP2(ev_);              \
    w_ = ((BB) + 2 < deg) ? w_ : 0.f;                                              \
    acc.x += w_ * V2.x; acc.y += w_ * V2.y; acc.z += w_ * V2.z; acc.w += w_ * V2.w; ssum += w_; \
    ev_ = sd + A3; ev_ = ev_ > 0.f ? ev_ : NEG * ev_; w_ = EXP2(ev_);              \
    w_ = ((BB) + 3 < deg) ? w_ : 0.f;                                              \
    acc.x += w_ * V3.x; acc.y += w_ * V3.y; acc.z += w_ * V3.z; acc.w += w_ * V3.w; ssum += w_; \
} while (0)

// K4: GAT layer, both layers in ONE launch (block range selects layer).
// One wave per node; chunk-4 software pipeline, manually 2x-unrolled into
// ping-pong register sets A/B (no rotation movs). launch_bounds(256,4)
// allows up to 128 VGPR so both chunks stay resident.
__global__ __launch_bounds__(256, 4) void k_gat(const float* __restrict__ h,
                                                const float* __restrict__ sd1, const float* __restrict__ ss1,
                                                const float* __restrict__ sd2, const float* __restrict__ ss2,
                                                const int* __restrict__ cnt,
                                                const int* __restrict__ slt1, const int* __restrict__ slt2,
                                                float* __restrict__ Z1, float* __restrict__ Z2) {
    int blk = blockIdx.x;
    const float* sdst = sd1; const float* ssrc = ss1;
    const int* cc = cnt; const int* sl = slt1; float* Z = Z1;
    if (blk >= NB1) { blk -= NB1; sdst = sd2; ssrc = ss2; cc = cnt + Nn; sl = slt2; Z = Z2; }
    int t = threadIdx.x;
    int lane = t & 63;
    int n = blk * 4 + (t >> 6);        // NB1*4 == Nn exactly
    int deg = cc[n]; if (deg > PAD) deg = PAD;
    int hh = lane >> 3;
    int sub = lane & 7;
    float sd = sdst[n * 8 + hh];
    int sval = sl[n * PAD + (lane & 31)];
    const float4* h4 = (const float4*)h;

    float ssum = 0.f;
    float4 acc = make_float4(0.f, 0.f, 0.f, 0.f);

    int as0, as1, as2, as3;  float aa0, aa1, aa2, aa3;  float4 av0, av1, av2, av3;
    int bs0, bs1, bs2, bs3;  float ba0, ba1, ba2, ba3;  float4 bv0, bv1, bv2, bv3;

    LOADC(as0, as1, as2, as3, aa0, aa1, aa2, aa3, av0, av1, av2, av3, 0);
    int base = 0;
    for (;;) {
        int nxt = base + 4;
        bool more = nxt < deg;          // wave-uniform
        if (more) LOADC(bs0, bs1, bs2, bs3, ba0, ba1, ba2, ba3, bv0, bv1, bv2, bv3, nxt);
        CONS(aa0, aa1, aa2, aa3, av0, av1, av2, av3, base);
        if (!more) break;
        base = nxt;
        nxt = base + 4;
        more = nxt < deg;
        if (more) LOADC(as0, as1, as2, as3, aa0, aa1, aa2, aa3, av0, av1, av2, av3, nxt);
        CONS(ba0, ba1, ba2, ba3, bv0, bv1, bv2, bv3, base);
        if (!more) break;
        base = nxt;
    }

    float inv = 1.f / ssum;
    float4 o;
    o.x = acc.x * inv; o.y = acc.y * inv; o.z = acc.z * inv; o.w = acc.w * inv;
    o.x = o.x > 0.f ? o.x : __expf(o.x) - 1.f;
    o.y = o.y > 0.f ? o.y : __expf(o.y) - 1.f;
    o.z = o.z > 0.f ? o.z : __expf(o.z) - 1.f;
    o.w = o.w > 0.f ? o.w : __expf(o.w) - 1.f;
    ((float4*)Z)[(size_t)n * 64 + lane] = o;
}

__device__ __forceinline__ float fast_tanh(float x) {
    return 1.f - 2.f / (1.f + __expf(2.f * x));
}

// K5: wave-independent MFMA score, both layers in ONE launch.
__global__ __launch_bounds__(256) void k_score(const float* __restrict__ Z1,
                        const float* __restrict__ Z2,
                        const short* __restrict__ fcwb,
                        const float* __restrict__ fcb,
                        const float* __restrict__ q,
                        float* __restrict__ Sacc) {
    int blk = blockIdx.x;
    const float* Z = Z1; float* bins = Sacc;
    if (blk >= NBS) { blk -= NBS; Z = Z2; bins = Sacc + 256; }
    int t = threadIdx.x;
    int lane = t & 63;
    int wid = t >> 6;
    int nodebase = blk * 64 + wid * 16;
    if (nodebase >= Nn) return;       // Nn % 16 == 0, wave-granular guard ok
    int col = lane & 15;
    int quad = lane >> 4;

    // load + convert all 8 A-fragments (16 float4 loads issue back-to-back)
    const float* zp = Z + (size_t)(nodebase + col) * Cc + quad * 8;
    bf16x8 af[8];
#pragma unroll
    for (int ks = 0; ks < 8; ++ks) {
        float4 f0 = *(const float4*)(zp + ks * 32);
        float4 f1 = *(const float4*)(zp + ks * 32 + 4);
        bf16x8 a;
        a[0] = f2bf(f0.x); a[1] = f2bf(f0.y); a[2] = f2bf(f0.z); a[3] = f2bf(f0.w);
        a[4] = f2bf(f1.x); a[5] = f2bf(f1.y); a[6] = f2bf(f1.z); a[7] = f2bf(f1.w);
        af[ks] = a;
    }

    f32x4 acc[8];
#pragma unroll
    for (int tt = 0; tt < 8; ++tt) { acc[tt][0] = 0.f; acc[tt][1] = 0.f; acc[tt][2] = 0.f; acc[tt][3] = 0.f; }

    const short* brow = fcwb + (size_t)col * Cc + quad * 8;
#pragma unroll
    for (int ks = 0; ks < 8; ++ks) {
#pragma unroll
        for (int tt = 0; tt < 8; ++tt) {
            bf16x8 b = *(const bf16x8*)(brow + tt * 4096 + ks * 32);
            acc[tt] = __builtin_amdgcn_mfma_f32_16x16x32_bf16(af[ks], b, acc[tt], 0, 0, 0);
        }
    }

    float local = 0.f;
#pragma unroll
    for (int tt = 0; tt < 8; ++tt) {
        int sem = tt * 16 + col;
        float b = fcb[sem], qq = q[sem];
#pragma unroll
        for (int r = 0; r < 4; ++r) local += fast_tanh(acc[tt][r] + b) * qq;
    }
#pragma unroll
    for (int off = 32; off > 0; off >>= 1) local += __shfl_down(local, off);
    if (lane == 0) atomicAdd(&bins[(blk & 15) * 16], local);
}

// K7: out = V0*out + V1*Z2; V from 16+16 score bins (stride-16 layout).
__global__ __launch_bounds__(256) void k_combine(float* __restrict__ out,
                                                 const float* __restrict__ Z2,
                                                 const float* __restrict__ S) {
    float s1 = 0.f, s2 = 0.f;
#pragma unroll
    for (int i = 0; i < 16; ++i) { s1 += S[i * 16]; s2 += S[256 + i * 16]; }
    s1 *= (1.f / (float)Nn);
    s2 *= (1.f / (float)Nn);
    float mx = fmaxf(s1, s2);
    float e1 = __expf(s1 - mx), e2 = __expf(s2 - mx);
    float inv = 1.f / (e1 + e2);
    float V0 = e1 * inv, V1 = e2 * inv;
    size_t i = (size_t)blockIdx.x * 256 + threadIdx.x;
    if (i < (size_t)Nn * 64) {
        float4 a = ((float4*)out)[i];
        float4 b = ((const float4*)Z2)[i];
        a.x = V0 * a.x + V1 * b.x;
        a.y = V0 * a.y + V1 * b.y;
        a.z = V0 * a.z + V1 * b.z;
        a.w = V0 * a.w + V1 * b.w;
        ((float4*)out)[i] = a;
    }
}

extern "C" void kernel_launch(void* const* d_in, const int* in_sizes, int n_in,
                              void* d_out, int out_size, void* d_ws, size_t ws_size,
                              hipStream_t stream) {
    const float* x    = (const float*)d_in[0];
    const float* W    = (const float*)d_in[1];
    const float* att1 = (const float*)d_in[2];
    const float* att2 = (const float*)d_in[3];
    const float* fcw  = (const float*)d_in[4];
    const float* fcb  = (const float*)d_in[5];
    const float* q    = (const float*)d_in[6];
    const int*   ei1  = (const int*)d_in[7];
    const int*   ei2  = (const int*)d_in[8];
    int E1 = in_sizes[7] / 2;
    int E2 = in_sizes[8] / 2;
    float* out = (float*)d_out;

    char* ws = (char*)d_ws;
    size_t off = 0;
    auto alloc = [&](size_t bytes) -> char* {
        char* p = ws + off;
        off = (off + bytes + 255) & ~(size_t)255;
        return p;
    };
    float* Z2   = (float*)alloc((size_t)Nn * Cc * 4);
    float* h    = (float*)alloc((size_t)Nn * Dd * 4);
    float* sd1  = (float*)alloc((size_t)Nn * Hh * 4);
    float* ss1  = (float*)alloc((size_t)Nn * Hh * 4);
    float* sd2  = (float*)alloc((size_t)Nn * Hh * 4);
    float* ss2  = (float*)alloc((size_t)Nn * Hh * 4);
    int*   cnt  = (int*)alloc((size_t)2 * Nn * 4);
    float* red  = (float*)alloc(2048);         // 2 sets x 16 bins, stride 16 floats
    float* Wt   = (float*)alloc((size_t)Dd * Cc * 4);
    short* fcwb = (short*)alloc((size_t)SEMk * Cc * 2);
    int*   slt1 = (int*)alloc((size_t)Nn * PAD * 4);
    int*   slt2 = (int*)alloc((size_t)Nn * PAD * 4);
    (void)ws_size; (void)n_in; (void)out_size;

    hipMemsetAsync(cnt, 0, (size_t)2 * Nn * 4, stream);
    hipMemsetAsync(red, 0, 2048, stream);

    k_prep<<<(SEMk * Cc + 255) / 256, 256, 0, stream>>>(W, Wt, fcw, fcwb);
    k_hproj<<<Nn / 32, 256, 0, stream>>>(x, Wt, att1, att2, h, sd1, ss1, sd2, ss2);
    k_scatter<<<(E1 + E2 + 255) / 256, 256, 0, stream>>>(ei1, E1, ei2, E2, cnt, slt1, slt2);
    k_gat<<<2 * NB1, 256, 0, stream>>>(h, sd1, ss1, sd2, ss2, cnt, slt1, slt2, out, Z2);
    k_score<<<2 * NBS, 256, 0, stream>>>(out, Z2, fcwb, fcb, q, red);
    k_combine<<<(Nn * 64) / 256, 256, 0, stream>>>(out, Z2, red);
}

// Round 7
// 542.505 us; speedup vs baseline: 1.2094x; 1.0017x over previous
//
#include <hip/hip_runtime.h>
#include <math.h>

#define Nn 100000
#define Cc 256
#define Dd 32
#define Hh 8
#define SEMk 128
#define PAD 32
#define NEG 0.2f
#define NBF 6250           // fused gat+score blocks per layer (16 nodes/block)

#if __has_builtin(__builtin_amdgcn_exp2f)
#define EXP2(x) __builtin_amdgcn_exp2f(x)
#else
#define EXP2(x) exp2f(x)
#endif
#define LOG2E 1.44269504088896f

typedef __attribute__((ext_vector_type(8))) short bf16x8;
typedef __attribute__((ext_vector_type(4))) short s16x4;
typedef __attribute__((ext_vector_type(4))) float f32x4;

__device__ __forceinline__ short f2bf(float f) {
    unsigned u = __float_as_uint(f);
    u = (u + 0x7FFF + ((u >> 16) & 1)) >> 16;   // round-to-nearest-even
    return (short)u;
}

// K0: Wt[j][k] = W[k][j] and fcwb = bf16(fc_w), one launch.
__global__ __launch_bounds__(256) void k_prep(const float* __restrict__ W,
                                              float* __restrict__ Wt,
                                              const float* __restrict__ fcw,
                                              short* __restrict__ fcwb) {
    int i = blockIdx.x * 256 + threadIdx.x;
    if (i < Dd * Cc) {
        int j = i >> 5, k = i & 31;
        Wt[i] = W[k * Cc + j];
    }
    if (i < SEMk * Cc) fcwb[i] = f2bf(fcw[i]);
}

// K1 (fused): h = x @ W^T, plus per-node attention projections for both layers.
// Scores are pre-scaled by log2e so k_gat can use bare v_exp_f32 (2^x):
// exp(leaky(d+s)) == 2^(leaky(L*d + L*s)) since leaky commutes with L>0.
__global__ __launch_bounds__(256) void k_hproj(const float* __restrict__ x,
                                               const float* __restrict__ Wt,
                                               const float* __restrict__ att1,
                                               const float* __restrict__ att2,
                                               float* __restrict__ h,
                                               float* __restrict__ sd1, float* __restrict__ ss1,
                                               float* __restrict__ sd2, float* __restrict__ ss2) {
    __shared__ float4 xs[32 * 65];
    __shared__ float  wt[256 * 36];
    __shared__ float4 hs[32 * 9];
    __shared__ float  a1[8 * 68];
    __shared__ float  a2[8 * 68];

    int t = threadIdx.x;
    int nb = blockIdx.x * 32;

    const float4* xg = (const float4*)x + (size_t)nb * 64;
#pragma unroll
    for (int it = 0; it < 8; ++it) {
        int i = t + it * 256;
        xs[(i >> 6) * 65 + (i & 63)] = xg[i];
    }
    const float4* wg = (const float4*)Wt;
#pragma unroll
    for (int it = 0; it < 8; ++it) {
        int i = t + it * 256;
        *(float4*)&wt[(i >> 3) * 36 + (i & 7) * 4] = wg[i];
    }
#pragma unroll
    for (int it = 0; it < 2; ++it) {
        int i = t + it * 256;
        a1[(i >> 6) * 68 + (i & 63)] = att1[i];
        a2[(i >> 6) * 68 + (i & 63)] = att2[i];
    }
    __syncthreads();

    int nl = t >> 3;
    int dq = t & 7;
    float4 acc = make_float4(0.f, 0.f, 0.f, 0.f);
    const float4* xr = &xs[nl * 65];
#pragma unroll 4
    for (int j4 = 0; j4 < 64; ++j4) {
        float4 xv = xr[j4];
        float4 w0 = *(const float4*)&wt[(j4 * 4 + 0) * 36 + dq * 4];
        float4 w1 = *(const float4*)&wt[(j4 * 4 + 1) * 36 + dq * 4];
        float4 w2 = *(const float4*)&wt[(j4 * 4 + 2) * 36 + dq * 4];
        float4 w3 = *(const float4*)&wt[(j4 * 4 + 3) * 36 + dq * 4];
        acc.x += xv.x * w0.x + xv.y * w1.x + xv.z * w2.x + xv.w * w3.x;
        acc.y += xv.x * w0.y + xv.y * w1.y + xv.z * w2.y + xv.w * w3.y;
        acc.z += xv.x * w0.z + xv.y * w1.z + xv.z * w2.z + xv.w * w3.z;
        acc.w += xv.x * w0.w + xv.y * w1.w + xv.z * w2.w + xv.w * w3.w;
    }
    ((float4*)h)[(size_t)(nb + nl) * 8 + dq] = acc;
    hs[nl * 9 + dq] = acc;
    __syncthreads();

    int nl2 = t >> 3;
    int hh = t & 7;
    float d1 = 0.f, s1 = 0.f, d2 = 0.f, s2 = 0.f;
#pragma unroll
    for (int d4 = 0; d4 < 8; ++d4) {
        float4 hv = hs[nl2 * 9 + d4];
        float4 ad1 = *(const float4*)&a1[hh * 68 + d4 * 4];
        float4 as1 = *(const float4*)&a1[hh * 68 + 32 + d4 * 4];
        float4 ad2 = *(const float4*)&a2[hh * 68 + d4 * 4];
        float4 as2 = *(const float4*)&a2[hh * 68 + 32 + d4 * 4];
        d1 += hv.x * ad1.x + hv.y * ad1.y + hv.z * ad1.z + hv.w * ad1.w;
        s1 += hv.x * as1.x + hv.y * as1.y + hv.z * as1.z + hv.w * as1.w;
        d2 += hv.x * ad2.x + hv.y * ad2.y + hv.z * ad2.z + hv.w * ad2.w;
        s2 += hv.x * as2.x + hv.y * as2.y + hv.z * as2.z + hv.w * as2.w;
    }
    int n = nb + nl2;
    sd1[n * 8 + hh] = d1 * LOG2E; ss1[n * 8 + hh] = s1 * LOG2E;
    sd2[n * 8 + hh] = d2 * LOG2E; ss2[n * 8 + hh] = s2 * LOG2E;
}

// K3: scatter edges of BOTH layers into padded per-dst slot lists, one launch.
__global__ __launch_bounds__(256) void k_scatter(const int* __restrict__ ei1, int E1,
                                                 const int* __restrict__ ei2, int E2,
                                                 int* __restrict__ cnt,
                                                 int* __restrict__ slt1,
                                                 int* __restrict__ slt2) {
    int id = blockIdx.x * 256 + threadIdx.x;
    const int* ei; int e, EE; int* c; int* sl;
    if (id < E1) { ei = ei1; e = id; EE = E1; c = cnt; sl = slt1; }
    else {
        e = id - E1;
        if (e >= E2) return;
        ei = ei2; EE = E2; c = cnt + Nn; sl = slt2;
    }
    int s = ei[e];
    int d = ei[EE + e];
    int pos = atomicAdd(&c[d], 1);
    if (pos < PAD) sl[d * PAD + pos] = s;
}

// ---- gat helper macros: load one chunk of 4 edges / consume it ----
#define LOADC(S0,S1,S2,S3,A0,A1,A2,A3,V0,V1,V2,V3,BB) do {                         \
    S0 = __shfl(sval, (BB) + 0); S1 = __shfl(sval, (BB) + 1);                      \
    S2 = __shfl(sval, (BB) + 2); S3 = __shfl(sval, (BB) + 3);                      \
    S1 = ((BB) + 1 < deg) ? S1 : n;                                                \
    S2 = ((BB) + 2 < deg) ? S2 : n;                                                \
    S3 = ((BB) + 3 < deg) ? S3 : n;                                                \
    A0 = ssrc[(unsigned)S0 * 8u + hh]; A1 = ssrc[(unsigned)S1 * 8u + hh];          \
    A2 = ssrc[(unsigned)S2 * 8u + hh]; A3 = ssrc[(unsigned)S3 * 8u + hh];          \
    V0 = h4[(unsigned)S0 * 8u + sub];  V1 = h4[(unsigned)S1 * 8u + sub];           \
    V2 = h4[(unsigned)S2 * 8u + sub];  V3 = h4[(unsigned)S3 * 8u + sub];           \
} while (0)

#define CONS(A0,A1,A2,A3,V0,V1,V2,V3,BB) do {                                      \
    float ev_, w_;                                                                 \
    ev_ = sd + A0; ev_ = ev_ > 0.f ? ev_ : NEG * ev_; w_ = EXP2(ev_);              \
    acc.x += w_ * V0.x; acc.y += w_ * V0.y; acc.z += w_ * V0.z; acc.w += w_ * V0.w; ssum += w_; \
    ev_ = sd + A1; ev_ = ev_ > 0.f ? ev_ : NEG * ev_; w_ = EXP2(ev_);              \
    w_ = ((BB) + 1 < deg) ? w_ : 0.f;                                              \
    acc.x += w_ * V1.x; acc.y += w_ * V1.y; acc.z += w_ * V1.z; acc.w += w_ * V1.w; ssum += w_; \
    ev_ = sd + A2; ev_ = ev_ > 0.f ? ev_ : NEG * ev_; w_ = EXP2(ev_);              \
    w_ = ((BB) + 2 < deg) ? w_ : 0.f;                                              \
    acc.x += w_ * V2.x; acc.y += w_ * V2.y; acc.z += w_ * V2.z; acc.w += w_ * V2.w; ssum += w_; \
    ev_ = sd + A3; ev_ = ev_ > 0.f ? ev_ : NEG * ev_; w_ = EXP2(ev_);              \
    w_ = ((BB) + 3 < deg) ? w_ : 0.f;                                              \
    acc.x += w_ * V3.x; acc.y += w_ * V3.y; acc.z += w_ * V3.z; acc.w += w_ * V3.w; ssum += w_; \
} while (0)

// K4 (fused GAT + score): 1024 thr = 16 waves = 16 nodes per block.
// Gat phase: wave = node, chunk-4 ping-pong pipeline (unchanged from the
//   proven Round-5/6 loop). Both layers in one grid (block range selects).
// Score phase: each wave stages its node's Z row as bf16 into a 16-row LDS
//   tile (ALL 16 rows valid -> full MFMA A-tile, same B traffic as the
//   standalone k_score). One __syncthreads; waves 0..7 each compute one
//   16-sem B tile (8x mfma_16x16x32_bf16), tanh(.+b)*q over all 16 node
//   rows, wave shfl-reduce, one atomicAdd per wave into 32 spread bins.
__global__ __launch_bounds__(1024, 8) void k_gatsc(const float* __restrict__ h,
                                                   const float* __restrict__ sd1, const float* __restrict__ ss1,
                                                   const float* __restrict__ sd2, const float* __restrict__ ss2,
                                                   const int* __restrict__ cnt,
                                                   const int* __restrict__ slt1, const int* __restrict__ slt2,
                                                   float* __restrict__ Z1, float* __restrict__ Z2,
                                                   const short* __restrict__ fcwb,
                                                   const float* __restrict__ fcb,
                                                   const float* __restrict__ q,
                                                   float* __restrict__ Sacc) {
    __shared__ short zls[16 * 264];    // 8448 B, row stride 264 shorts
    int blk = blockIdx.x;
    const float* sdst = sd1; const float* ssrc = ss1;
    const int* cc = cnt; const int* sl = slt1; float* Z = Z1;
    float* bins = Sacc;
    if (blk >= NBF) { blk -= NBF; sdst = sd2; ssrc = ss2; cc = cnt + Nn; sl = slt2; Z = Z2; bins = Sacc + 256; }
    int t = threadIdx.x;
    int lane = t & 63;
    int wid = t >> 6;                  // node-in-block 0..15
    int n = blk * 16 + wid;            // NBF*16 == Nn exactly
    int deg = cc[n]; if (deg > PAD) deg = PAD;
    int hh = lane >> 3;
    int sub = lane & 7;
    float sd = sdst[n * 8 + hh];
    int sval = sl[n * PAD + (lane & 31)];
    const float4* h4 = (const float4*)h;

    float ssum = 0.f;
    float4 acc = make_float4(0.f, 0.f, 0.f, 0.f);

    int as0, as1, as2, as3;  float aa0, aa1, aa2, aa3;  float4 av0, av1, av2, av3;
    int bs0, bs1, bs2, bs3;  float ba0, ba1, ba2, ba3;  float4 bv0, bv1, bv2, bv3;

    LOADC(as0, as1, as2, as3, aa0, aa1, aa2, aa3, av0, av1, av2, av3, 0);
    int base = 0;
    for (;;) {
        int nxt = base + 4;
        bool more = nxt < deg;          // wave-uniform
        if (more) LOADC(bs0, bs1, bs2, bs3, ba0, ba1, ba2, ba3, bv0, bv1, bv2, bv3, nxt);
        CONS(aa0, aa1, aa2, aa3, av0, av1, av2, av3, base);
        if (!more) break;
        base = nxt;
        nxt = base + 4;
        more = nxt < deg;
        if (more) LOADC(as0, as1, as2, as3, aa0, aa1, aa2, aa3, av0, av1, av2, av3, nxt);
        CONS(ba0, ba1, ba2, ba3, bv0, bv1, bv2, bv3, base);
        if (!more) break;
        base = nxt;
    }

    float inv = 1.f / ssum;
    float4 o;
    o.x = acc.x * inv; o.y = acc.y * inv; o.z = acc.z * inv; o.w = acc.w * inv;
    o.x = o.x > 0.f ? o.x : __expf(o.x) - 1.f;
    o.y = o.y > 0.f ? o.y : __expf(o.y) - 1.f;
    o.z = o.z > 0.f ? o.z : __expf(o.z) - 1.f;
    o.w = o.w > 0.f ? o.w : __expf(o.w) - 1.f;
    ((float4*)Z)[(size_t)n * 64 + lane] = o;

    // stage bf16 row for score MFMA (node wid's 256 values, contiguous)
    s16x4 b4;
    b4[0] = f2bf(o.x); b4[1] = f2bf(o.y); b4[2] = f2bf(o.z); b4[3] = f2bf(o.w);
    *(s16x4*)&zls[wid * 264 + lane * 4] = b4;
    __syncthreads();

    if (wid >= 8) return;              // waves 8..15 done (after barrier: safe)

    // score: A = 16 staged node rows; wave w -> sems [w*16, w*16+16)
    int col = lane & 15;
    int quad = lane >> 4;
    const short* zrow = &zls[col * 264 + quad * 8];
    const short* brow = fcwb + (size_t)(wid * 16 + col) * Cc + quad * 8;
    f32x4 sacc;
    sacc[0] = 0.f; sacc[1] = 0.f; sacc[2] = 0.f; sacc[3] = 0.f;
#pragma unroll
    for (int ks = 0; ks < 8; ++ks) {
        bf16x8 a = *(const bf16x8*)(zrow + ks * 32);
        bf16x8 b = *(const bf16x8*)(brow + ks * 32);
        sacc = __builtin_amdgcn_mfma_f32_16x16x32_bf16(a, b, sacc, 0, 0, 0);
    }
    float local = 0.f;
    {
        int sem = wid * 16 + col;
        float bb = fcb[sem], qq = q[sem];
#pragma unroll
        for (int r = 0; r < 4; ++r) local += (1.f - 2.f / (1.f + __expf(2.f * (sacc[r] + bb)))) * qq;
    }
#pragma unroll
    for (int off = 32; off > 0; off >>= 1) local += __shfl_down(local, off);
    if (lane == 0) atomicAdd(&bins[(blk & 31) * 8], local);
}

// K7: out = V0*out + V1*Z2; V from 32+32 score bins (stride-8 layout).
__global__ __launch_bounds__(256) void k_combine(float* __restrict__ out,
                                                 const float* __restrict__ Z2,
                                                 const float* __restrict__ S) {
    float s1 = 0.f, s2 = 0.f;
#pragma unroll
    for (int i = 0; i < 32; ++i) { s1 += S[i * 8]; s2 += S[256 + i * 8]; }
    s1 *= (1.f / (float)Nn);
    s2 *= (1.f / (float)Nn);
    float mx = fmaxf(s1, s2);
    float e1 = __expf(s1 - mx), e2 = __expf(s2 - mx);
    float inv = 1.f / (e1 + e2);
    float V0 = e1 * inv, V1 = e2 * inv;
    size_t i = (size_t)blockIdx.x * 256 + threadIdx.x;
    if (i < (size_t)Nn * 64) {
        float4 a = ((float4*)out)[i];
        float4 b = ((const float4*)Z2)[i];
        a.x = V0 * a.x + V1 * b.x;
        a.y = V0 * a.y + V1 * b.y;
        a.z = V0 * a.z + V1 * b.z;
        a.w = V0 * a.w + V1 * b.w;
        ((float4*)out)[i] = a;
    }
}

extern "C" void kernel_launch(void* const* d_in, const int* in_sizes, int n_in,
                              void* d_out, int out_size, void* d_ws, size_t ws_size,
                              hipStream_t stream) {
    const float* x    = (const float*)d_in[0];
    const float* W    = (const float*)d_in[1];
    const float* att1 = (const float*)d_in[2];
    const float* att2 = (const float*)d_in[3];
    const float* fcw  = (const float*)d_in[4];
    const float* fcb  = (const float*)d_in[5];
    const float* q    = (const float*)d_in[6];
    const int*   ei1  = (const int*)d_in[7];
    const int*   ei2  = (const int*)d_in[8];
    int E1 = in_sizes[7] / 2;
    int E2 = in_sizes[8] / 2;
    float* out = (float*)d_out;

    char* ws = (char*)d_ws;
    size_t off = 0;
    auto alloc = [&](size_t bytes) -> char* {
        char* p = ws + off;
        off = (off + bytes + 255) & ~(size_t)255;
        return p;
    };
    float* Z2   = (float*)alloc((size_t)Nn * Cc * 4);
    float* h    = (float*)alloc((size_t)Nn * Dd * 4);
    float* sd1  = (float*)alloc((size_t)Nn * Hh * 4);
    float* ss1  = (float*)alloc((size_t)Nn * Hh * 4);
    float* sd2  = (float*)alloc((size_t)Nn * Hh * 4);
    float* ss2  = (float*)alloc((size_t)Nn * Hh * 4);
    int*   cnt  = (int*)alloc((size_t)2 * Nn * 4);
    float* red  = (float*)alloc(2048);         // 2 sets x 32 bins, stride 8 floats
    float* Wt   = (float*)alloc((size_t)Dd * Cc * 4);
    short* fcwb = (short*)alloc((size_t)SEMk * Cc * 2);
    int*   slt1 = (int*)alloc((size_t)Nn * PAD * 4);
    int*   slt2 = (int*)alloc((size_t)Nn * PAD * 4);
    (void)ws_size; (void)n_in; (void)out_size;

    hipMemsetAsync(cnt, 0, (size_t)2 * Nn * 4, stream);
    hipMemsetAsync(red, 0, 2048, stream);

    k_prep<<<(SEMk * Cc + 255) / 256, 256, 0, stream>>>(W, Wt, fcw, fcwb);
    k_hproj<<<Nn / 32, 256, 0, stream>>>(x, Wt, att1, att2, h, sd1, ss1, sd2, ss2);
    k_scatter<<<(E1 + E2 + 255) / 256, 256, 0, stream>>>(ei1, E1, ei2, E2, cnt, slt1, slt2);
    k_gatsc<<<2 * NBF, 1024, 0, stream>>>(h, sd1, ss1, sd2, ss2, cnt, slt1, slt2,
                                          out, Z2, fcwb, fcb, q, red);
    k_combine<<<(Nn * 64) / 256, 256, 0, stream>>>(out, Z2, red);
}

// Round 8
// 528.795 us; speedup vs baseline: 1.2408x; 1.0259x over previous
//
#include <hip/hip_runtime.h>
#include <math.h>

#define Nn 100000
#define Cc 256
#define Dd 32
#define Hh 8
#define SEMk 128
#define PAD 32
#define NEG 0.2f
#define NB1 25000          // k_gat blocks per layer (4 nodes/block)
#define NTASK 12500        // k_score wave-tasks total (6250 per layer)

#if __has_builtin(__builtin_amdgcn_exp2f)
#define EXP2(x) __builtin_amdgcn_exp2f(x)
#else
#define EXP2(x) exp2f(x)
#endif
#define LOG2E 1.44269504088896f

typedef __attribute__((ext_vector_type(8))) short bf16x8;
typedef __attribute__((ext_vector_type(4))) short s16x4;
typedef __attribute__((ext_vector_type(4))) float f32x4;

__device__ __forceinline__ short f2bf(float f) {
    unsigned u = __float_as_uint(f);
    u = (u + 0x7FFF + ((u >> 16) & 1)) >> 16;   // round-to-nearest-even
    return (short)u;
}

// K0: Wt[j][k] = W[k][j] and fcwb = bf16(fc_w), one launch.
__global__ __launch_bounds__(256) void k_prep(const float* __restrict__ W,
                                              float* __restrict__ Wt,
                                              const float* __restrict__ fcw,
                                              short* __restrict__ fcwb) {
    int i = blockIdx.x * 256 + threadIdx.x;
    if (i < Dd * Cc) {
        int j = i >> 5, k = i & 31;
        Wt[i] = W[k * Cc + j];
    }
    if (i < SEMk * Cc) fcwb[i] = f2bf(fcw[i]);
}

// K1 (fused): h = x @ W^T, plus per-node attention projections for both layers.
// Scores pre-scaled by log2e so k_gat uses bare v_exp_f32 (2^x):
// exp(leaky(d+s)) == 2^(leaky(L*d + L*s)) since leaky commutes with L>0.
__global__ __launch_bounds__(256) void k_hproj(const float* __restrict__ x,
                                               const float* __restrict__ Wt,
                                               const float* __restrict__ att1,
                                               const float* __restrict__ att2,
                                               float* __restrict__ h,
                                               float* __restrict__ sd1, float* __restrict__ ss1,
                                               float* __restrict__ sd2, float* __restrict__ ss2) {
    __shared__ float4 xs[32 * 65];
    __shared__ float  wt[256 * 36];
    __shared__ float4 hs[32 * 9];
    __shared__ float  a1[8 * 68];
    __shared__ float  a2[8 * 68];

    int t = threadIdx.x;
    int nb = blockIdx.x * 32;

    const float4* xg = (const float4*)x + (size_t)nb * 64;
#pragma unroll
    for (int it = 0; it < 8; ++it) {
        int i = t + it * 256;
        xs[(i >> 6) * 65 + (i & 63)] = xg[i];
    }
    const float4* wg = (const float4*)Wt;
#pragma unroll
    for (int it = 0; it < 8; ++it) {
        int i = t + it * 256;
        *(float4*)&wt[(i >> 3) * 36 + (i & 7) * 4] = wg[i];
    }
#pragma unroll
    for (int it = 0; it < 2; ++it) {
        int i = t + it * 256;
        a1[(i >> 6) * 68 + (i & 63)] = att1[i];
        a2[(i >> 6) * 68 + (i & 63)] = att2[i];
    }
    __syncthreads();

    int nl = t >> 3;
    int dq = t & 7;
    float4 acc = make_float4(0.f, 0.f, 0.f, 0.f);
    const float4* xr = &xs[nl * 65];
#pragma unroll 4
    for (int j4 = 0; j4 < 64; ++j4) {
        float4 xv = xr[j4];
        float4 w0 = *(const float4*)&wt[(j4 * 4 + 0) * 36 + dq * 4];
        float4 w1 = *(const float4*)&wt[(j4 * 4 + 1) * 36 + dq * 4];
        float4 w2 = *(const float4*)&wt[(j4 * 4 + 2) * 36 + dq * 4];
        float4 w3 = *(const float4*)&wt[(j4 * 4 + 3) * 36 + dq * 4];
        acc.x += xv.x * w0.x + xv.y * w1.x + xv.z * w2.x + xv.w * w3.x;
        acc.y += xv.x * w0.y + xv.y * w1.y + xv.z * w2.y + xv.w * w3.y;
        acc.z += xv.x * w0.z + xv.y * w1.z + xv.z * w2.z + xv.w * w3.z;
        acc.w += xv.x * w0.w + xv.y * w1.w + xv.z * w2.w + xv.w * w3.w;
    }
    ((float4*)h)[(size_t)(nb + nl) * 8 + dq] = acc;
    hs[nl * 9 + dq] = acc;
    __syncthreads();

    int nl2 = t >> 3;
    int hh = t & 7;
    float d1 = 0.f, s1 = 0.f, d2 = 0.f, s2 = 0.f;
#pragma unroll
    for (int d4 = 0; d4 < 8; ++d4) {
        float4 hv = hs[nl2 * 9 + d4];
        float4 ad1 = *(const float4*)&a1[hh * 68 + d4 * 4];
        float4 as1 = *(const float4*)&a1[hh * 68 + 32 + d4 * 4];
        float4 ad2 = *(const float4*)&a2[hh * 68 + d4 * 4];
        float4 as2 = *(const float4*)&a2[hh * 68 + 32 + d4 * 4];
        d1 += hv.x * ad1.x + hv.y * ad1.y + hv.z * ad1.z + hv.w * ad1.w;
        s1 += hv.x * as1.x + hv.y * as1.y + hv.z * as1.z + hv.w * as1.w;
        d2 += hv.x * ad2.x + hv.y * ad2.y + hv.z * ad2.z + hv.w * ad2.w;
        s2 += hv.x * as2.x + hv.y * as2.y + hv.z * as2.z + hv.w * as2.w;
    }
    int n = nb + nl2;
    sd1[n * 8 + hh] = d1 * LOG2E; ss1[n * 8 + hh] = s1 * LOG2E;
    sd2[n * 8 + hh] = d2 * LOG2E; ss2[n * 8 + hh] = s2 * LOG2E;
}

// K3: scatter edges of BOTH layers into padded per-dst slot lists, one launch.
__global__ __launch_bounds__(256) void k_scatter(const int* __restrict__ ei1, int E1,
                                                 const int* __restrict__ ei2, int E2,
                                                 int* __restrict__ cnt,
                                                 int* __restrict__ slt1,
                                                 int* __restrict__ slt2) {
    int id = blockIdx.x * 256 + threadIdx.x;
    const int* ei; int e, EE; int* c; int* sl;
    if (id < E1) { ei = ei1; e = id; EE = E1; c = cnt; sl = slt1; }
    else {
        e = id - E1;
        if (e >= E2) return;
        ei = ei2; EE = E2; c = cnt + Nn; sl = slt2;
    }
    int s = ei[e];
    int d = ei[EE + e];
    int pos = atomicAdd(&c[d], 1);
    if (pos < PAD) sl[d * PAD + pos] = s;
}

// ---- gat helper macros: load one chunk of 4 edges / consume it ----
#define LOADC(S0,S1,S2,S3,A0,A1,A2,A3,V0,V1,V2,V3,BB) do {                         \
    S0 = __shfl(sval, (BB) + 0); S1 = __shfl(sval, (BB) + 1);                      \
    S2 = __shfl(sval, (BB) + 2); S3 = __shfl(sval, (BB) + 3);                      \
    S1 = ((BB) + 1 < deg) ? S1 : n;                                                \
    S2 = ((BB) + 2 < deg) ? S2 : n;                                                \
    S3 = ((BB) + 3 < deg) ? S3 : n;                                                \
    A0 = ssrc[(unsigned)S0 * 8u + hh]; A1 = ssrc[(unsigned)S1 * 8u + hh];          \
    A2 = ssrc[(unsigned)S2 * 8u + hh]; A3 = ssrc[(unsigned)S3 * 8u + hh];          \
    V0 = h4[(unsigned)S0 * 8u + sub];  V1 = h4[(unsigned)S1 * 8u + sub];           \
    V2 = h4[(unsigned)S2 * 8u + sub];  V3 = h4[(unsigned)S3 * 8u + sub];           \
} while (0)

#define CONS(A0,A1,A2,A3,V0,V1,V2,V3,BB) do {                                      \
    float ev_, w_;                                                                 \
    ev_ = sd + A0; ev_ = ev_ > 0.f ? ev_ : NEG * ev_; w_ = EXP2(ev_);              \
    acc.x += w_ * V0.x; acc.y += w_ * V0.y; acc.z += w_ * V0.z; acc.w += w_ * V0.w; ssum += w_; \
    ev_ = sd + A1; ev_ = ev_ > 0.f ? ev_ : NEG * ev_; w_ = EXP2(ev_);              \
    w_ = ((BB) + 1 < deg) ? w_ : 0.f;                                              \
    acc.x += w_ * V1.x; acc.y += w_ * V1.y; acc.z += w_ * V1.z; acc.w += w_ * V1.w; ssum += w_; \
    ev_ = sd + A2; ev_ = ev_ > 0.f ? ev_ : NEG * ev_; w_ = EXP2(ev_);              \
    w_ = ((BB) + 2 < deg) ? w_ : 0.f;                                              \
    acc.x += w_ * V2.x; acc.y += w_ * V2.y; acc.z += w_ * V2.z; acc.w += w_ * V2.w; ssum += w_; \
    ev_ = sd + A3; ev_ = ev_ > 0.f ? ev_ : NEG * ev_; w_ = EXP2(ev_);              \
    w_ = ((BB) + 3 < deg) ? w_ : 0.f;                                              \
    acc.x += w_ * V3.x; acc.y += w_ * V3.y; acc.z += w_ * V3.z; acc.w += w_ * V3.w; ssum += w_; \
} while (0)

// K4: GAT layer, both layers in ONE launch (block range selects layer).
// One wave per node; chunk-4 ping-pong pipeline (round-6 proven form).
__global__ __launch_bounds__(256, 4) void k_gat(const float* __restrict__ h,
                                                const float* __restrict__ sd1, const float* __restrict__ ss1,
                                                const float* __restrict__ sd2, const float* __restrict__ ss2,
                                                const int* __restrict__ cnt,
                                                const int* __restrict__ slt1, const int* __restrict__ slt2,
                                                float* __restrict__ Z1, float* __restrict__ Z2) {
    int blk = blockIdx.x;
    const float* sdst = sd1; const float* ssrc = ss1;
    const int* cc = cnt; const int* sl = slt1; float* Z = Z1;
    if (blk >= NB1) { blk -= NB1; sdst = sd2; ssrc = ss2; cc = cnt + Nn; sl = slt2; Z = Z2; }
    int t = threadIdx.x;
    int lane = t & 63;
    int n = blk * 4 + (t >> 6);        // NB1*4 == Nn exactly
    int deg = cc[n]; if (deg > PAD) deg = PAD;
    int hh = lane >> 3;
    int sub = lane & 7;
    float sd = sdst[n * 8 + hh];
    int sval = sl[n * PAD + (lane & 31)];
    const float4* h4 = (const float4*)h;

    float ssum = 0.f;
    float4 acc = make_float4(0.f, 0.f, 0.f, 0.f);

    int as0, as1, as2, as3;  float aa0, aa1, aa2, aa3;  float4 av0, av1, av2, av3;
    int bs0, bs1, bs2, bs3;  float ba0, ba1, ba2, ba3;  float4 bv0, bv1, bv2, bv3;

    LOADC(as0, as1, as2, as3, aa0, aa1, aa2, aa3, av0, av1, av2, av3, 0);
    int base = 0;
    for (;;) {
        int nxt = base + 4;
        bool more = nxt < deg;          // wave-uniform
        if (more) LOADC(bs0, bs1, bs2, bs3, ba0, ba1, ba2, ba3, bv0, bv1, bv2, bv3, nxt);
        CONS(aa0, aa1, aa2, aa3, av0, av1, av2, av3, base);
        if (!more) break;
        base = nxt;
        nxt = base + 4;
        more = nxt < deg;
        if (more) LOADC(as0, as1, as2, as3, aa0, aa1, aa2, aa3, av0, av1, av2, av3, nxt);
        CONS(ba0, ba1, ba2, ba3, bv0, bv1, bv2, bv3, base);
        if (!more) break;
        base = nxt;
    }

    float inv = 1.f / ssum;
    float4 o;
    o.x = acc.x * inv; o.y = acc.y * inv; o.z = acc.z * inv; o.w = acc.w * inv;
    o.x = o.x > 0.f ? o.x : __expf(o.x) - 1.f;
    o.y = o.y > 0.f ? o.y : __expf(o.y) - 1.f;
    o.z = o.z > 0.f ? o.z : __expf(o.z) - 1.f;
    o.w = o.w > 0.f ? o.w : __expf(o.w) - 1.f;
    ((float4*)Z)[(size_t)n * 64 + lane] = o;
}

__device__ __forceinline__ float fast_tanh(float x) {
    return 1.f - 2.f / (1.f + __expf(2.f * x));
}

// byte-offset XOR swizzle within a 1KB row (bits 4..6 <- row&7)
#define SWZ(off, r) ((off) ^ (((r) & 7) << 4))

// K5 v5: MFMA score with global_load_lds A-staging (zero-VGPR in-flight loads).
// 256 thr = 4 waves; each wave owns one 16-node tile and a private 16KB LDS
// region. Stage 16 rows x 1KB via 16x global_load_lds (dest linear, source
// pre-swizzled per rule "both-sides-or-neither"); vmcnt(0); read fragments
// back with the same XOR (conflict-free-ish banks); convert to bf16; then the
// round-6 proven MFMA loop (B from global fcwb, L2-hot). One atomic per wave.
__global__ __launch_bounds__(256) void k_score(const float* __restrict__ Z1,
                        const float* __restrict__ Z2,
                        const short* __restrict__ fcwb,
                        const float* __restrict__ fcb,
                        const float* __restrict__ q,
                        float* __restrict__ Sacc) {
    __shared__ float zst[4 * 4096];    // 16 KB per wave, 64 KB total
    int t = threadIdx.x;
    int lane = t & 63;
    int wid = t >> 6;
    int task = blockIdx.x * 4 + wid;   // 0..NTASK-1, grid exact
    const float* Z = Z1; float* bins = Sacc;
    int tile = task;
    if (task >= NTASK / 2) { Z = Z2; bins = Sacc + 256; tile = task - NTASK / 2; }
    int nodebase = tile * 16;
    float* myst = &zst[wid * 4096];

    // ---- stage 16 rows x 1KB, LDS linear, global source pre-swizzled ----
    const char* zb = (const char*)(Z + (size_t)nodebase * Cc);
#pragma unroll
    for (int r = 0; r < 16; ++r) {
        const char* src = zb + r * 1024 + SWZ(lane * 16, r);
        __builtin_amdgcn_global_load_lds(
            (const __attribute__((address_space(1))) void*)src,
            (__attribute__((address_space(3))) void*)(myst + r * 256),
            16, 0, 0);
    }
    asm volatile("s_waitcnt vmcnt(0)" ::: "memory");
    __builtin_amdgcn_sched_barrier(0);

    int col = lane & 15;
    int quad = lane >> 4;

    // ---- read + convert 8 A-fragments from swizzled LDS ----
    const char* rowp = (const char*)myst + col * 1024;
    bf16x8 af[8];
#pragma unroll
    for (int ks = 0; ks < 8; ++ks) {
        int b0 = ks * 128 + quad * 32;
        float4 f0 = *(const float4*)(rowp + SWZ(b0, col));
        float4 f1 = *(const float4*)(rowp + SWZ(b0 + 16, col));
        bf16x8 a;
        a[0] = f2bf(f0.x); a[1] = f2bf(f0.y); a[2] = f2bf(f0.z); a[3] = f2bf(f0.w);
        a[4] = f2bf(f1.x); a[5] = f2bf(f1.y); a[6] = f2bf(f1.z); a[7] = f2bf(f1.w);
        af[ks] = a;
    }

    f32x4 acc[8];
#pragma unroll
    for (int tt = 0; tt < 8; ++tt) { acc[tt][0] = 0.f; acc[tt][1] = 0.f; acc[tt][2] = 0.f; acc[tt][3] = 0.f; }

    const short* brow = fcwb + (size_t)col * Cc + quad * 8;
#pragma unroll
    for (int ks = 0; ks < 8; ++ks) {
        bf16x8 bf[8];
#pragma unroll
        for (int tt = 0; tt < 8; ++tt)
            bf[tt] = *(const bf16x8*)(brow + tt * 4096 + ks * 32);
#pragma unroll
        for (int tt = 0; tt < 8; ++tt)
            acc[tt] = __builtin_amdgcn_mfma_f32_16x16x32_bf16(af[ks], bf[tt], acc[tt], 0, 0, 0);
    }

    float local = 0.f;
#pragma unroll
    for (int tt = 0; tt < 8; ++tt) {
        int sem = tt * 16 + col;
        float b = fcb[sem], qq = q[sem];
#pragma unroll
        for (int r = 0; r < 4; ++r) local += fast_tanh(acc[tt][r] + b) * qq;
    }
#pragma unroll
    for (int off = 32; off > 0; off >>= 1) local += __shfl_down(local, off);
    if (lane == 0) atomicAdd(&bins[(task & 31) * 8], local);
}

// K7: out = V0*out + V1*Z2; V from 32+32 score bins (stride-8 layout).
__global__ __launch_bounds__(256) void k_combine(float* __restrict__ out,
                                                 const float* __restrict__ Z2,
                                                 const float* __restrict__ S) {
    float s1 = 0.f, s2 = 0.f;
#pragma unroll
    for (int i = 0; i < 32; ++i) { s1 += S[i * 8]; s2 += S[256 + i * 8]; }
    s1 *= (1.f / (float)Nn);
    s2 *= (1.f / (float)Nn);
    float mx = fmaxf(s1, s2);
    float e1 = __expf(s1 - mx), e2 = __expf(s2 - mx);
    float inv = 1.f / (e1 + e2);
    float V0 = e1 * inv, V1 = e2 * inv;
    size_t i = (size_t)blockIdx.x * 256 + threadIdx.x;
    if (i < (size_t)Nn * 64) {
        float4 a = ((float4*)out)[i];
        float4 b = ((const float4*)Z2)[i];
        a.x = V0 * a.x + V1 * b.x;
        a.y = V0 * a.y + V1 * b.y;
        a.z = V0 * a.z + V1 * b.z;
        a.w = V0 * a.w + V1 * b.w;
        ((float4*)out)[i] = a;
    }
}

extern "C" void kernel_launch(void* const* d_in, const int* in_sizes, int n_in,
                              void* d_out, int out_size, void* d_ws, size_t ws_size,
                              hipStream_t stream) {
    const float* x    = (const float*)d_in[0];
    const float* W    = (const float*)d_in[1];
    const float* att1 = (const float*)d_in[2];
    const float* att2 = (const float*)d_in[3];
    const float* fcw  = (const float*)d_in[4];
    const float* fcb  = (const float*)d_in[5];
    const float* q    = (const float*)d_in[6];
    const int*   ei1  = (const int*)d_in[7];
    const int*   ei2  = (const int*)d_in[8];
    int E1 = in_sizes[7] / 2;
    int E2 = in_sizes[8] / 2;
    float* out = (float*)d_out;

    char* ws = (char*)d_ws;
    size_t off = 0;
    auto alloc = [&](size_t bytes) -> char* {
        char* p = ws + off;
        off = (off + bytes + 255) & ~(size_t)255;
        return p;
    };
    float* Z2   = (float*)alloc((size_t)Nn * Cc * 4);
    float* h    = (float*)alloc((size_t)Nn * Dd * 4);
    float* sd1  = (float*)alloc((size_t)Nn * Hh * 4);
    float* ss1  = (float*)alloc((size_t)Nn * Hh * 4);
    float* sd2  = (float*)alloc((size_t)Nn * Hh * 4);
    float* ss2  = (float*)alloc((size_t)Nn * Hh * 4);
    int*   cnt  = (int*)alloc((size_t)2 * Nn * 4);
    float* red  = (float*)alloc(2048);         // 2 sets x 32 bins, stride 8 floats
    float* Wt   = (float*)alloc((size_t)Dd * Cc * 4);
    short* fcwb = (short*)alloc((size_t)SEMk * Cc * 2);
    int*   slt1 = (int*)alloc((size_t)Nn * PAD * 4);
    int*   slt2 = (int*)alloc((size_t)Nn * PAD * 4);
    (void)ws_size; (void)n_in; (void)out_size;

    hipMemsetAsync(cnt, 0, (size_t)2 * Nn * 4, stream);
    hipMemsetAsync(red, 0, 2048, stream);

    k_prep<<<(SEMk * Cc + 255) / 256, 256, 0, stream>>>(W, Wt, fcw, fcwb);
    k_hproj<<<Nn / 32, 256, 0, stream>>>(x, Wt, att1, att2, h, sd1, ss1, sd2, ss2);
    k_scatter<<<(E1 + E2 + 255) / 256, 256, 0, stream>>>(ei1, E1, ei2, E2, cnt, slt1, slt2);
    k_gat<<<2 * NB1, 256, 0, stream>>>(h, sd1, ss1, sd2, ss2, cnt, slt1, slt2, out, Z2);
    k_score<<<NTASK / 4, 256, 0, stream>>>(out, Z2, fcwb, fcb, q, red);
    k_combine<<<(Nn * 64) / 256, 256, 0, stream>>>(out, Z2, red);
}